// Round 15
// baseline (530.852 us; speedup 1.0000x reference)
//
#include <hip/hip_runtime.h>

typedef unsigned short u16;
typedef unsigned int u32;
typedef __attribute__((ext_vector_type(8))) short short8;
typedef __attribute__((ext_vector_type(4))) float floatx4;

#define P_PAIRS 160000
#define N_ATOMS 10000

#define OFF_WMLP  0      // stored TRANSPOSED: [50][64], (o,k) at o*64+k
#define OFF_BMLP  3200
#define OFF_WE1   3250
#define OFF_BE1   6930
#define OFF_WE2   6962
#define OFF_BE2   7986
#define OFF_WATT  8018
#define OFF_BATT  8242
#define OFF_WN1   8249
#define OFF_BN1   17465
#define OFF_WN2   17497
#define OFF_BN2   18521
#define OFF_WP1   18553
#define OFF_BP1   25721
#define OFF_WP2   25753
#define OFF_BP2   26777
#define OFF_WV1   26809
#define OFF_BV1   27833
#define OFF_WV2   27865
#define OFF_WVMIX 27897
#define WF_TOTAL  28121

__device__ __forceinline__ float b2f(u16 u){ return __uint_as_float(((u32)u) << 16); }
__device__ __forceinline__ u16 f2b(float f){
  u32 u = __float_as_uint(f);
  u32 r = (u + 0x7FFFu + ((u >> 16) & 1u)) >> 16;
  return (u16)r;
}
__device__ __forceinline__ void unpack2(u32 p, float& lo, float& hi){
  lo = __uint_as_float(p << 16);
  hi = __uint_as_float(p & 0xFFFF0000u);
}
__device__ __forceinline__ float siluf(float v){ return v / (1.f + __expf(-v)); }
__device__ __forceinline__ float ldw(const void* p, int o, int bf){
  return bf ? b2f(((const u16*)p)[o]) : ((const float*)p)[o];
}

__global__ void k_code(float* out, float code){
  if (threadIdx.x == 0 && blockIdx.x == 0) out[0] = code;
}

// per-block dtype detection (wave 0 ballot)
__device__ __forceinline__ void detect_flags(const u32* hw, const u32* plw, int* s_fl){
  int tid = threadIdx.x;
  if (tid < 64){
    u32 e = (hw[tid] >> 7) & 0xFFu;
    unsigned long long m1 = __ballot(e >= 100u && e <= 140u);
    unsigned long long m2 = __ballot(plw[2*tid+1] == 0u);
    if (tid == 0){
      s_fl[0] = (__popcll(m1) >= 48) ? 1 : 0;
      s_fl[1] = (__popcll(m2) >= 60) ? 1 : 0;
    }
  }
  __syncthreads();
}

// ------------- fused preprocessing: norm + convert + transpose + bpk + hist -
#define NBP_NORM 2735
#define NBP_CONV (NBP_NORM + 110)
#define NBP_TRAN (NBP_CONV + 196)
#define NBP_PB   (NBP_TRAN + 14)
#define NBP_HIST (NBP_PB + 625)

__global__ void k_prep(const void* __restrict__ h_raw, const void* __restrict__ x_raw,
    const void* __restrict__ v_raw, const void* __restrict__ pl_raw,
    const void* w_mlp, const void* b_mlp, const void* w_e1, const void* b_e1,
    const void* w_e2, const void* b_e2, const void* w_att, const void* b_att,
    const void* w_n1, const void* b_n1, const void* w_n2, const void* b_n2,
    const void* w_p1, const void* b_p1, const void* w_p2, const void* b_p2,
    const void* w_v1, const void* b_v1, const void* w_v2, const void* w_vmix,
    const void* wx,
    float* __restrict__ hf, float* __restrict__ xf, float* __restrict__ vf,
    int* __restrict__ pli, float* __restrict__ Wf, u16* __restrict__ wT,
    u16* __restrict__ bpk, int* __restrict__ counts){
  __shared__ int s_fl[2];
  detect_flags((const u32*)h_raw, (const u32*)pl_raw, s_fl);
  int bf = s_fl[0], i64 = s_fl[1];
  int bid = blockIdx.x, tid = threadIdx.x;
  if (bid < NBP_NORM){
    int t = bid * 256 + tid;
    if (t < 320000){
      hf[t] = ldw(h_raw, t, bf);
    } else if (t < 350000){
      int i = t - 320000; xf[i] = ldw(x_raw, i, bf);
    } else if (t < 380000){
      int i = t - 350000; vf[i] = ldw(v_raw, i, bf);
    } else if (t < 700000){
      int k = t - 380000;
      const int* p32 = (const int*)pl_raw;
      pli[k] = i64 ? p32[2*(size_t)k] : p32[k];
    }
  } else if (bid < NBP_CONV){
    int t = (bid - NBP_NORM) * 256 + tid;
    if (t >= WF_TOTAL) return;
    if (t < 3200){
      int k = t / 50, o = t - k * 50;
      Wf[OFF_WMLP + o * 64 + k] = ldw(w_mlp, t, bf);
      return;
    }
    const void* src; int o;
    if      (t < 3250)  { src = b_mlp;  o = t - 3200; }
    else if (t < 6930)  { src = w_e1;   o = t - 3250; }
    else if (t < 6962)  { src = b_e1;   o = t - 6930; }
    else if (t < 7986)  { src = w_e2;   o = t - 6962; }
    else if (t < 8018)  { src = b_e2;   o = t - 7986; }
    else if (t < 8242)  { src = w_att;  o = t - 8018; }
    else if (t < 8249)  { src = b_att;  o = t - 8242; }
    else if (t < 17465) { src = w_n1;   o = t - 8249; }
    else if (t < 17497) { src = b_n1;   o = t - 17465; }
    else if (t < 18521) { src = w_n2;   o = t - 17497; }
    else if (t < 18553) { src = b_n2;   o = t - 18521; }
    else if (t < 25721) { src = w_p1;   o = t - 18553; }
    else if (t < 25753) { src = b_p1;   o = t - 25721; }
    else if (t < 26777) { src = w_p2;   o = t - 25753; }
    else if (t < 26809) { src = b_p2;   o = t - 26777; }
    else if (t < 27833) { src = w_v1;   o = t - 26809; }
    else if (t < 27865) { src = b_v1;   o = t - 27833; }
    else if (t < 27897) { src = w_v2;   o = t - 27865; }
    else                { src = w_vmix; o = t - 27897; }
    Wf[t] = ldw(src, o, bf);
  } else if (bid < NBP_TRAN){
    int t = (bid - NBP_CONV) * 256 + tid;
    if (t >= 224 * 224) return;
    int n = t / 224, k = t - n * 224;
    wT[t] = f2b(ldw(wx, k * 224 + n, bf));
  } else if (bid < NBP_PB){
    // bpk: B1T [32][64] | B2T [32][32] | B3T [16][32]  (bf16, from RAW weights)
    int t = (bid - NBP_TRAN) * 256 + tid;
    if (t >= 3584) return;
    float v = 0.f;
    if (t < 2048){
      int n = t >> 6, k = t & 63;
      if (k < 50)       v = ldw(w_e1, (64 + k) * 32 + n, bf);
      else if (k == 50) v = ldw(w_e1, 114 * 32 + n, bf);
    } else if (t < 3072){
      int e = t - 2048; int n = e >> 5, k = e & 31;
      v = ldw(w_e2, k * 32 + n, bf);
    } else {
      int e = t - 3072; int n = e >> 5, k = e & 31;
      if (n < 7) v = ldw(w_att, k * 7 + n, bf);
    }
    bpk[t] = f2b(v);
  } else {
    int p = (bid - NBP_PB) * 256 + tid;     // hist from raw pairlist
    const int* p32 = (const int*)pl_raw;
    int i = i64 ? p32[2*(size_t)p] : p32[p];
    atomicAdd(&counts[i], 1);
  }
}

// ---------- fused: per-atom projections (625 fat blocks) + scan (1 block) ---
__global__ void k_atomscan(const float* __restrict__ hf, const float* __restrict__ Wf,
    u16* __restrict__ prei, u16* __restrict__ prej,
    const int* __restrict__ counts, int* __restrict__ offs, int* __restrict__ cursor){
  __shared__ float hs[16][33];
  __shared__ int part[256];
  int tid = threadIdx.x;
  if (blockIdx.x < 625){
    int a0 = blockIdx.x * 16;
    for (int e = tid; e < 512; e += 256){
      int a = e >> 5, k = e & 31;
      hs[a][k] = hf[(size_t)(a0 + a) * 32 + k];
    }
    __syncthreads();
    for (int e = tid; e < 800; e += 256){
      int a = e / 50, r = e - a * 50;
      const float* wm = Wf + OFF_WMLP + r * 64;
      float acc = Wf[OFF_BMLP + r];
      #pragma unroll
      for (int k = 0; k < 32; ++k) acc += hs[a][k] * wm[k];
      prei[(size_t)(a0 + a) * 88 + 32 + r] = f2b(acc);
    }
    for (int e = tid; e < 800; e += 256){
      int a = e / 50, r = e - a * 50;
      const float* wm = Wf + OFF_WMLP + r * 64 + 32;
      float acc = 0.f;
      #pragma unroll
      for (int k = 0; k < 32; ++k) acc += hs[a][k] * wm[k];
      prej[(size_t)(a0 + a) * 88 + 32 + r] = f2b(acc);
    }
    for (int e = tid; e < 512; e += 256){
      int a = e >> 5, o = e & 31;
      float acc = Wf[OFF_BE1 + o];
      #pragma unroll
      for (int k = 0; k < 32; ++k) acc += hs[a][k] * Wf[OFF_WE1 + k * 32 + o];
      prei[(size_t)(a0 + a) * 88 + o] = f2b(acc);
    }
    for (int e = tid; e < 512; e += 256){
      int a = e >> 5, o = e & 31;
      float acc = 0.f;
      #pragma unroll
      for (int k = 0; k < 32; ++k) acc += hs[a][k] * Wf[OFF_WE1 + (32 + k) * 32 + o];
      prej[(size_t)(a0 + a) * 88 + o] = f2b(acc);
    }
  } else {
    int sum = 0;
    for (int k = 0; k < 40; ++k){
      int idx = tid * 40 + k;
      if (idx < N_ATOMS) sum += counts[idx];
    }
    part[tid] = sum;
    __syncthreads();
    if (tid == 0){
      int run = 0;
      for (int q = 0; q < 256; ++q){ int tmp = part[q]; part[q] = run; run += tmp; }
    }
    __syncthreads();
    int run = part[tid];
    for (int k = 0; k < 40; ++k){
      int idx = tid * 40 + k;
      if (idx < N_ATOMS){ offs[idx] = run; cursor[idx] = run; run += counts[idx]; }
    }
    if (tid == 0) offs[N_ATOMS] = P_PAIRS;
  }
}

__global__ void k_scatter(const int* __restrict__ pl, int* __restrict__ cursor,
                          int* __restrict__ isrt, int* __restrict__ jsrt){
  int p = blockIdx.x * 256 + threadIdx.x;
  int i = pl[p];
  int pos = atomicAdd(&cursor[i], 1);
  isrt[pos] = i;
  jsrt[pos] = pl[P_PAIRS + p];
}

// ------- per-pair edge model via MFMA: 128 pairs/block, 4 waves -------------
#define PM_UB   0
#define PM_TB   16384
#define PM_DD   30720
#define PM_A1   31232
#define PM_B1   49664
#define PM_A2   54272
#define PM_B2   64512
#define PM_B3   67072
#define PM_TOT  68352

__global__ __launch_bounds__(256) void k_pairm(const float* __restrict__ x,
    const float* __restrict__ Wf, const u16* __restrict__ prei, const u16* __restrict__ prej,
    const int* __restrict__ isrt, const int* __restrict__ jsrt, const u16* __restrict__ bpk,
    u16* __restrict__ edge, float* __restrict__ logits, float* __restrict__ dirs){
  __shared__ __attribute__((aligned(16))) char smem[PM_TOT];
  float* UB = (float*)(smem + PM_UB);
  u16*   TB = (u16*)(smem + PM_TB);
  float* DD = (float*)(smem + PM_DD);
  u16*   A1 = (u16*)(smem + PM_A1);
  u16*   B1 = (u16*)(smem + PM_B1);
  u16*   A2 = (u16*)(smem + PM_A2);
  u16*   B2 = (u16*)(smem + PM_B2);
  u16*   B3 = (u16*)(smem + PM_B3);
  int tid = threadIdx.x;
  int wave = tid >> 6, lane = tid & 63, l15 = lane & 15, quad = lane >> 4;
  int row0 = blockIdx.x * 128;

  if (tid < 128){
    int s = row0 + tid;
    int i = isrt[s], j = jsrt[s];
    float r0 = x[j*3+0] - x[i*3+0];
    float r1 = x[j*3+1] - x[i*3+1];
    float r2 = x[j*3+2] - x[i*3+2];
    float d = sqrtf(r0*r0 + r1*r1 + r2*r2);
    float rinv = 1.f / (d + 1e-5f);
    dirs[s*3+0] = r0*rinv; dirs[s*3+1] = r1*rinv; dirs[s*3+2] = r2*rinv;
    DD[tid] = d;
    const uint4* pi4 = (const uint4*)(prei + (size_t)i * 88);
    const uint4* pj4 = (const uint4*)(prej + (size_t)j * 88);
    float* ub = UB + tid * 32;
    #pragma unroll
    for (int q = 0; q < 4; ++q){
      uint4 a4 = pi4[q], b4 = pj4[q];
      u32 pa[4] = {a4.x, a4.y, a4.z, a4.w};
      u32 pb[4] = {b4.x, b4.y, b4.z, b4.w};
      #pragma unroll
      for (int w2 = 0; w2 < 4; ++w2){
        float al, ah, bl, bh;
        unpack2(pa[w2], al, ah); unpack2(pb[w2], bl, bh);
        ub[q*8 + w2*2]     = al + bl;
        ub[q*8 + w2*2 + 1] = ah + bh;
      }
    }
    u32* tb = (u32*)TB + tid * 28;
    #pragma unroll
    for (int q = 0; q < 7; ++q){
      uint4 a4 = pi4[4+q], b4 = pj4[4+q];
      u32 pa[4] = {a4.x, a4.y, a4.z, a4.w};
      u32 pb[4] = {b4.x, b4.y, b4.z, b4.w};
      #pragma unroll
      for (int w2 = 0; w2 < 4; ++w2){
        float al, ah, bl, bh;
        unpack2(pa[w2], al, ah); unpack2(pb[w2], bl, bh);
        tb[q*4 + w2] = (u32)f2b(al + bl) | ((u32)f2b(ah + bh) << 16);
      }
    }
  } else {
    int t2 = tid - 128;
    const u32* src = (const u32*)bpk;
    for (int e = t2; e < 1024; e += 128){         // B1T [32][64] -> stride 36 u32
      int n = e >> 5, kp = e & 31;
      ((u32*)B1)[n*36 + kp] = src[e];
    }
    for (int e = t2; e < 512; e += 128){          // B2T [32][32] -> stride 20 u32
      int n = e >> 4, kp = e & 15;
      ((u32*)B2)[n*20 + kp] = src[1024 + e];
    }
    for (int e = t2; e < 256; e += 128){          // B3T [16][32] -> stride 20 u32
      int n = e >> 4, kp = e & 15;
      ((u32*)B3)[n*20 + kp] = src[1536 + e];
    }
  }
  __syncthreads();
  // A1 [128][72-stride]: cols 0..49 filt, col 50 = d, 51..63 = 0
  for (int e = tid; e < 4096; e += 256){
    int r = e >> 5, kp = e & 31;
    int k0 = kp * 2, k1 = k0 + 1;
    float d = DD[r];
    float v0 = 0.f, v1 = 0.f;
    if (k0 < 50){
      float t0 = b2f(TB[r*56 + k0]);
      float c0 = (float)k0 * (5.f/49.f), dd0 = d - c0;
      v0 = t0 * __expf(-10.f * dd0 * dd0);
    } else if (k0 == 50) v0 = d;
    if (k1 < 50){
      float t1 = b2f(TB[r*56 + k1]);
      float c1 = (float)k1 * (5.f/49.f), dd1 = d - c1;
      v1 = t1 * __expf(-10.f * dd1 * dd1);
    }
    ((u32*)A1)[r*36 + kp] = (u32)f2b(v0) | ((u32)f2b(v1) << 16);
  }
  __syncthreads();
  // u = A1 @ B1 + UB  (M=128 N=32 K=64)
  floatx4 au[2][2];
  #pragma unroll
  for (int mt = 0; mt < 2; ++mt)
    #pragma unroll
    for (int nt = 0; nt < 2; ++nt) au[mt][nt] = (floatx4){0.f,0.f,0.f,0.f};
  #pragma unroll
  for (int ks = 0; ks < 2; ++ks){
    int kk = ks * 32;
    short8 a0 = *(const short8*)(A1 + (wave*32 + l15)*72 + kk + quad*8);
    short8 a1 = *(const short8*)(A1 + (wave*32 + 16 + l15)*72 + kk + quad*8);
    #pragma unroll
    for (int nt = 0; nt < 2; ++nt){
      short8 b = *(const short8*)(B1 + (nt*16 + l15)*72 + kk + quad*8);
      au[0][nt] = __builtin_amdgcn_mfma_f32_16x16x32_bf16(a0, b, au[0][nt], 0, 0, 0);
      au[1][nt] = __builtin_amdgcn_mfma_f32_16x16x32_bf16(a1, b, au[1][nt], 0, 0, 0);
    }
  }
  #pragma unroll
  for (int mt = 0; mt < 2; ++mt)
    #pragma unroll
    for (int nt = 0; nt < 2; ++nt)
      #pragma unroll
      for (int reg = 0; reg < 4; ++reg){
        int r = wave*32 + mt*16 + quad*4 + reg;
        int c = nt*16 + l15;
        float uval = au[mt][nt][reg] + UB[r*32 + c];
        A2[r*40 + c] = f2b(siluf(uval));
      }
  __syncthreads();
  // eg = A2 @ B2 (M=128 N=32 K=32)
  floatx4 ae[2][2];
  #pragma unroll
  for (int mt = 0; mt < 2; ++mt)
    #pragma unroll
    for (int nt = 0; nt < 2; ++nt) ae[mt][nt] = (floatx4){0.f,0.f,0.f,0.f};
  {
    short8 a0 = *(const short8*)(A2 + (wave*32 + l15)*40 + quad*8);
    short8 a1 = *(const short8*)(A2 + (wave*32 + 16 + l15)*40 + quad*8);
    #pragma unroll
    for (int nt = 0; nt < 2; ++nt){
      short8 b = *(const short8*)(B2 + (nt*16 + l15)*40 + quad*8);
      ae[0][nt] = __builtin_amdgcn_mfma_f32_16x16x32_bf16(a0, b, ae[0][nt], 0, 0, 0);
      ae[1][nt] = __builtin_amdgcn_mfma_f32_16x16x32_bf16(a1, b, ae[1][nt], 0, 0, 0);
    }
  }
  __syncthreads();    // all A2 (silu-u) reads done before overwrite with eg
  #pragma unroll
  for (int mt = 0; mt < 2; ++mt)
    #pragma unroll
    for (int nt = 0; nt < 2; ++nt)
      #pragma unroll
      for (int reg = 0; reg < 4; ++reg){
        int r = wave*32 + mt*16 + quad*4 + reg;
        int c = nt*16 + l15;
        float ev = ae[mt][nt][reg] + Wf[OFF_BE2 + c];
        A2[r*40 + c] = f2b(ev);
      }
  __syncthreads();
  // edge copy-out (coalesced)
  {
    int r = tid >> 1, p = tid & 1;
    const uint4* srcp = (const uint4*)(A2 + r*40 + p*16);
    uint4* dstp = (uint4*)(edge + (size_t)(row0 + r)*32 + p*16);
    dstp[0] = srcp[0]; dstp[1] = srcp[1];
  }
  // logits = celu(A2 @ B3 + batt)  (N=16, 7 used)
  floatx4 al_[2];
  al_[0] = (floatx4){0.f,0.f,0.f,0.f};
  al_[1] = (floatx4){0.f,0.f,0.f,0.f};
  {
    short8 a0 = *(const short8*)(A2 + (wave*32 + l15)*40 + quad*8);
    short8 a1 = *(const short8*)(A2 + (wave*32 + 16 + l15)*40 + quad*8);
    short8 b = *(const short8*)(B3 + l15*40 + quad*8);
    al_[0] = __builtin_amdgcn_mfma_f32_16x16x32_bf16(a0, b, al_[0], 0, 0, 0);
    al_[1] = __builtin_amdgcn_mfma_f32_16x16x32_bf16(a1, b, al_[1], 0, 0, 0);
  }
  if (l15 < 7){
    float ba = Wf[OFF_BATT + l15];
    #pragma unroll
    for (int mt = 0; mt < 2; ++mt)
      #pragma unroll
      for (int reg = 0; reg < 4; ++reg){
        int r = wave*32 + mt*16 + quad*4 + reg;
        float vv = al_[mt][reg] + ba;
        float cl = vv > 0.f ? vv : 2.f * expm1f(0.5f * vv);
        logits[(size_t)(row0 + r)*7 + l15] = cl;
      }
  }
}

// -------- segment softmax + hsem accumulation (16-lane group per atom) ------
__global__ __launch_bounds__(256) void k_att(const int* __restrict__ offs,
    const float* __restrict__ logits, const u16* __restrict__ edge,
    float* __restrict__ atts, float* __restrict__ hsem){
  int a = blockIdx.x * 16 + (threadIdx.x >> 4);   // N = 625*16
  int lane = threadIdx.x & 15;
  int off = offs[a], end = offs[a+1];
  float m[7];
  #pragma unroll
  for (int hh = 0; hh < 7; ++hh) m[hh] = -1e30f;
  for (int s = off + lane; s < end; s += 16){
    #pragma unroll
    for (int hh = 0; hh < 7; ++hh) m[hh] = fmaxf(m[hh], logits[s*7+hh]);
  }
  #pragma unroll
  for (int hh = 0; hh < 7; ++hh){
    float v = m[hh];
    #pragma unroll
    for (int msk = 8; msk >= 1; msk >>= 1) v = fmaxf(v, __shfl_xor(v, msk));
    m[hh] = v;
  }
  float sm[7] = {0,0,0,0,0,0,0};
  for (int s = off + lane; s < end; s += 16){
    #pragma unroll
    for (int hh = 0; hh < 7; ++hh){
      float e = __expf(logits[s*7+hh] - m[hh]);
      sm[hh] += e;
      atts[s*7+hh] = e;
    }
  }
  #pragma unroll
  for (int hh = 0; hh < 7; ++hh){
    float v = sm[hh];
    #pragma unroll
    for (int msk = 8; msk >= 1; msk >>= 1) v += __shfl_xor(v, msk);
    sm[hh] = 1.f / v;
  }
  for (int s = off + lane; s < end; s += 16){
    #pragma unroll
    for (int hh = 0; hh < 7; ++hh) atts[s*7+hh] *= sm[hh];
  }
  __syncthreads();
  float acc[14] = {0,0,0,0,0,0,0,0,0,0,0,0,0,0};
  for (int s = off; s < end; ++s){
    u32 ev = *(const u32*)(edge + (size_t)s * 32 + lane * 2);
    float e0 = b2f((u16)(ev & 0xFFFFu));
    float e1 = b2f((u16)(ev >> 16));
    const float* ap = atts + (size_t)s * 7;
    #pragma unroll
    for (int hh = 0; hh < 7; ++hh){
      float at = ap[hh];
      acc[hh]     += e0 * at;
      acc[7 + hh] += e1 * at;
    }
  }
  float* hp = hsem + (size_t)a * 224 + lane * 14;
  #pragma unroll
  for (int jj = 0; jj < 14; ++jj) hp[jj] = acc[jj];
}

// -------- MFMA GEMM fast path: M=64, N=224, ONE A-pack, chunked Bs ----------
// LDS: As [64][232]u16 = 29696 (xth overlays in place after MFMA, stride 232)
//      Bs [112][40]u16 = 8960 @29696 (eL [64][36]=4608 + aL 1792 overlay)
// 14 stage+MFMA phases (half x kt); single pack/stage/epilogue per 64 rows.
#define GF_BS   29696
#define GF_EL   29696
#define GF_AL   (29696 + 4608)
#define GF_TOT  38656

__global__ __launch_bounds__(256, 4) void k_gemm3f(const u16* __restrict__ edge,
    const float* __restrict__ atts, const u16* __restrict__ BT,
    u16* __restrict__ xh0, u16* __restrict__ xh1){
  __shared__ __attribute__((aligned(16))) char smem[GF_TOT];
  u16*   As  = (u16*)smem;                 // stride 232 u16 (116 u32)
  u16*   xth = (u16*)smem;                 // in-place after MFMA, stride 232
  u16*   Bs  = (u16*)(smem + GF_BS);       // stride 40 u16, 112 rows
  u16*   eL  = (u16*)(smem + GF_EL);       // stride 36 u16 (dead after pack)
  float* aL  = (float*)(smem + GF_AL);     // stride 7 floats (dead after pack)
  int tid = threadIdx.x;
  int wave = tid >> 6, lane = tid & 63, l15 = lane & 15, quad = lane >> 4;
  int row0 = blockIdx.x * 64;

  // stage edge rows (padded stride 36) + atts
  for (int e = tid; e < 512; e += 256){
    int r = e >> 3, q = e & 7;
    *(uint2*)(eL + r*36 + q*4) = *(const uint2*)(edge + (size_t)(row0 + r)*32 + q*4);
  }
  for (int e = tid; e < 448; e += 256) aL[e] = atts[(size_t)row0*7 + e];
  floatx4 acc[14];
  #pragma unroll
  for (int nt = 0; nt < 14; ++nt) acc[nt] = (floatx4){0.f, 0.f, 0.f, 0.f};
  __syncthreads();

  // pack full-K A-tile ONCE: thread t -> row t>>2, quarter (t&3)*56 cols
  {
    int pr = tid >> 2, q = tid & 3;
    u32* asw = (u32*)As + pr*116 + q*28;
    const u16* er = eL + pr*36 + q*8;
    const float* ar = aL + pr*7;
    float av[7];
    #pragma unroll
    for (int hh = 0; hh < 7; ++hh) av[hh] = ar[hh];
    #pragma unroll
    for (int fo2 = 0; fo2 < 4; ++fo2){
      float e0 = b2f(er[2*fo2]);
      float e1 = b2f(er[2*fo2+1]);
      u16 w[14];
      #pragma unroll
      for (int hh = 0; hh < 7; ++hh){
        w[hh]   = f2b(e0 * av[hh]);
        w[7+hh] = f2b(e1 * av[hh]);
      }
      #pragma unroll
      for (int k = 0; k < 7; ++k)
        asw[fo2*7 + k] = (u32)w[2*k] | ((u32)w[2*k+1] << 16);
    }
  }
  __syncthreads();          // As ready; eL/aL dead -> Bs usable

  // 14 phases: half in {0,1} x kt in {0..6}; 7 MFMA per phase
  #pragma unroll 1
  for (int half = 0; half < 2; ++half){
    int nbase = half * 112;
    #pragma unroll 1
    for (int kt = 0; kt < 7; ++kt){
      for (int e = tid; e < 448; e += 256){
        int r = e >> 2, q = e & 3;
        *(uint4*)(Bs + r*40 + q*8) = *(const uint4*)(BT + (size_t)(nbase + r)*224 + kt*32 + q*8);
      }
      __syncthreads();
      short8 a0 = *(const short8*)(As + (wave*16 + l15)*232 + kt*32 + quad*8);
      #pragma unroll
      for (int nt = 0; nt < 7; ++nt){
        short8 b = *(const short8*)(Bs + (nt*16 + l15)*40 + quad*8);
        acc[half*7 + nt] = __builtin_amdgcn_mfma_f32_16x16x32_bf16(a0, b, acc[half*7 + nt], 0, 0, 0);
      }
      __syncthreads();      // MFMA reads done before next stage overwrites Bs
    }
  }

  // tanh epilogue -> xth in place (stride 232), full 224 cols
  #pragma unroll
  for (int nt = 0; nt < 14; ++nt)
    #pragma unroll
    for (int reg = 0; reg < 4; ++reg){
      int r = wave*16 + quad*4 + reg;
      int c = nt*16 + l15;
      float vv = acc[nt][reg];
      vv = fminf(fmaxf(vv, -15.f), 15.f);
      float e2 = __expf(2.f * vv);
      xth[r*232 + c] = f2b((e2 - 1.f) / (e2 + 1.f));
    }
  __syncthreads();
  // coalesced copy-out: 64 rows x 28 uint4 (first 14 -> xh0, last 14 -> xh1)
  for (int e = tid; e < 1792; e += 256){
    int r = e / 28, w = e - r * 28;
    uint4 val = *(const uint4*)(xth + r*232 + w*8);
    if (w < 14) *(uint4*)(xh0 + (size_t)(row0 + r)*112 + w*8) = val;
    else        *(uint4*)(xh1 + (size_t)(row0 + r)*112 + (w-14)*8) = val;
  }
}

// -------- MFMA GEMM fallback (round-11-proven, per-half / paired) -----------
#define G_BS   29696
#define G_EL   29696
#define G_AL   (29696 + 4608)
#define G_TOT  38656

__global__ __launch_bounds__(256, 4) void k_gemm3(const u16* __restrict__ edge,
    const float* __restrict__ atts, const u16* __restrict__ BT,
    u16* __restrict__ xh0, u16* __restrict__ xh1, int mode){
  __shared__ __attribute__((aligned(16))) char smem[G_TOT];
  u16*   As  = (u16*)smem;
  u16*   xth = (u16*)smem;                 // stride 120, overlays As after MFMA
  u16*   Bs  = (u16*)(smem + G_BS);
  u16*   eL  = (u16*)(smem + G_EL);
  float* aL  = (float*)(smem + G_AL);
  int tid = threadIdx.x;
  int wave = tid >> 6, lane = tid & 63, l15 = lane & 15, quad = lane >> 4;
  int bid = blockIdx.x;
  int half, rblk;
  if (mode < 0){ half = bid & 1; rblk = bid >> 1; }
  else         { half = mode;    rblk = bid; }
  u16* xhalf = half ? xh1 : xh0;
  int row0 = rblk * 64;
  int nbase = half * 112;

  for (int e = tid; e < 512; e += 256){
    int r = e >> 3, q = e & 7;
    *(uint2*)(eL + r*36 + q*4) = *(const uint2*)(edge + (size_t)(row0 + r)*32 + q*4);
  }
  for (int e = tid; e < 448; e += 256) aL[e] = atts[(size_t)row0*7 + e];
  floatx4 acc[7];
  #pragma unroll
  for (int nt = 0; nt < 7; ++nt) acc[nt] = (floatx4){0.f, 0.f, 0.f, 0.f};
  __syncthreads();

  {
    int pr = tid >> 2, q = tid & 3;
    u32* asw = (u32*)As + pr*116 + q*28;
    const u16* er = eL + pr*36 + q*8;
    const float* ar = aL + pr*7;
    float av[7];
    #pragma unroll
    for (int hh = 0; hh < 7; ++hh) av[hh] = ar[hh];
    #pragma unroll
    for (int fo2 = 0; fo2 < 4; ++fo2){
      float e0 = b2f(er[2*fo2]);
      float e1 = b2f(er[2*fo2+1]);
      u16 w[14];
      #pragma unroll
      for (int hh = 0; hh < 7; ++hh){
        w[hh]   = f2b(e0 * av[hh]);
        w[7+hh] = f2b(e1 * av[hh]);
      }
      #pragma unroll
      for (int k = 0; k < 7; ++k)
        asw[fo2*7 + k] = (u32)w[2*k] | ((u32)w[2*k+1] << 16);
    }
  }
  __syncthreads();

  for (int kt = 0; kt < 7; ++kt){
    for (int e = tid; e < 448; e += 256){
      int r = e >> 2, q = e & 3;
      *(uint4*)(Bs + r*40 + q*8) = *(const uint4*)(BT + (size_t)(nbase + r)*224 + kt*32 + q*8);
    }
    __syncthreads();
    int kk = kt * 32;
    short8 a0 = *(const short8*)(As + (wave*16 + l15)*232 + kk + quad*8);
    #pragma unroll
    for (int nt = 0; nt < 7; ++nt){
      short8 b = *(const short8*)(Bs + (nt*16 + l15)*40 + quad*8);
      acc[nt] = __builtin_amdgcn_mfma_f32_16x16x32_bf16(a0, b, acc[nt], 0, 0, 0);
    }
    __syncthreads();
  }

  #pragma unroll
  for (int nt = 0; nt < 7; ++nt)
    #pragma unroll
    for (int reg = 0; reg < 4; ++reg){
      int r = wave*16 + quad*4 + reg;
      int c = nt*16 + l15;
      float vv = acc[nt][reg];
      vv = fminf(fmaxf(vv, -15.f), 15.f);
      float e2 = __expf(2.f * vv);
      xth[r*120 + c] = f2b((e2 - 1.f) / (e2 + 1.f));
    }
  __syncthreads();
  for (int e = tid; e < 896; e += 256){
    int r = e / 14, w = e - r * 14;
    *(uint4*)(xhalf + (size_t)(row0 + r)*112 + w*8) = *(const uint4*)(xth + r*120 + w*8);
  }
}

// -------- atom-centric comb reduction (fallback path) -----------------------
__global__ __launch_bounds__(256) void k_comb(const int* __restrict__ offs,
    const u16* __restrict__ xhalf, const float* __restrict__ dirs,
    const float* __restrict__ Wf, int half,
    float* __restrict__ nsq, float* __restrict__ pvh){
  int a = blockIdx.x * 16 + (threadIdx.x >> 4);
  int lane = threadIdx.x & 15;
  int off = offs[a], end = offs[a+1];
  float c0[7] = {0,0,0,0,0,0,0}, c1[7] = {0,0,0,0,0,0,0}, c2[7] = {0,0,0,0,0,0,0};
  for (int s = off; s < end; ++s){
    float d0 = dirs[s*3+0], d1 = dirs[s*3+1], d2 = dirs[s*3+2];
    const u16* xr = xhalf + (size_t)s * 112 + lane;
    #pragma unroll
    for (int k = 0; k < 7; ++k){
      float xm = b2f(xr[k*16]);
      c0[k] += d0 * xm; c1[k] += d1 * xm; c2[k] += d2 * xm;
    }
  }
  float inv = 1.f / fmaxf((float)(end - off), 1.f);
  float pv0 = 0.f, pv1 = 0.f, pv2 = 0.f;
  #pragma unroll
  for (int k = 0; k < 7; ++k){
    float m0 = c0[k]*inv, m1 = c1[k]*inv, m2 = c2[k]*inv;
    int c = half*112 + k*16 + lane;
    nsq[(size_t)a*224 + c] = m0*m0 + m1*m1 + m2*m2;
    float wv = Wf[OFF_WVMIX + c];
    pv0 += wv*m0; pv1 += wv*m1; pv2 += wv*m2;
  }
  #pragma unroll
  for (int m = 8; m >= 1; m >>= 1){
    pv0 += __shfl_xor(pv0, m); pv1 += __shfl_xor(pv1, m); pv2 += __shfl_xor(pv2, m);
  }
  if (lane == 0){
    float* pp = pvh + (size_t)half*30000 + (size_t)a*3;
    pp[0] = pv0; pp[1] = pv1; pp[2] = pv2;
  }
}

// ------- final (fallback path): 16 atoms/block, 2 atoms/thread --------------
__global__ __launch_bounds__(256) void k_final4(const float* __restrict__ h,
    const float* __restrict__ x, const float* __restrict__ v,
    const float* __restrict__ Wf, const float* __restrict__ hsem,
    const float* __restrict__ nsq, const float* __restrict__ pvh,
    float* __restrict__ out){
  __shared__ float s_nsq[16][225];
  __shared__ float s_in[16][289];
  __shared__ float s_u1[16][33];
  __shared__ float s_un[16][33];
  __shared__ float s_sc[16];
  int tid = threadIdx.x;
  int a0 = blockIdx.x * 16;
  for (int e = tid; e < 896; e += 256){
    int a = e / 56, q = e - a * 56;
    float4 t = *(const float4*)(nsq + (size_t)(a0 + a) * 224 + q * 4);
    s_nsq[a][q*4+0] = t.x; s_nsq[a][q*4+1] = t.y;
    s_nsq[a][q*4+2] = t.z; s_nsq[a][q*4+3] = t.w;
  }
  for (int e = tid; e < 896; e += 256){
    int a = e / 56, q = e - a * 56;
    float4 t = *(const float4*)(hsem + (size_t)(a0 + a) * 224 + q * 4);
    s_in[a][32 + q*4+0] = t.x; s_in[a][32 + q*4+1] = t.y;
    s_in[a][32 + q*4+2] = t.z; s_in[a][32 + q*4+3] = t.w;
  }
  for (int e = tid; e < 128; e += 256){
    int a = e >> 3, q = e & 7;
    float4 t = *(const float4*)(h + (size_t)(a0 + a) * 32 + q * 4);
    s_in[a][q*4+0] = t.x; s_in[a][q*4+1] = t.y;
    s_in[a][q*4+2] = t.z; s_in[a][q*4+3] = t.w;
  }
  __syncthreads();
  int o = tid & 31, g5 = tid >> 5;
  int aA = g5, aB = g5 + 8;
  {
    float uA = Wf[OFF_BP1 + o], uB = uA;
    const float* w = Wf + OFF_WP1 + o;
    #pragma unroll 8
    for (int kk = 0; kk < 224; ++kk){
      float wv = w[kk*32];
      uA += s_nsq[aA][kk] * wv;
      uB += s_nsq[aB][kk] * wv;
    }
    s_u1[aA][o] = siluf(uA);
    s_u1[aB][o] = siluf(uB);
  }
  {
    float gA = Wf[OFF_BV1 + o], gB = gA;
    const float* w = Wf + OFF_WV1 + o;
    #pragma unroll
    for (int kk = 0; kk < 32; ++kk){
      float wv = w[kk*32];
      gA += s_in[aA][kk] * wv;
      gB += s_in[aB][kk] * wv;
    }
    float wv2 = Wf[OFF_WV2 + o];
    float zA = siluf(gA) * wv2, zB = siluf(gB) * wv2;
    #pragma unroll
    for (int m = 16; m >= 1; m >>= 1){
      zA += __shfl_xor(zA, m); zB += __shfl_xor(zB, m);
    }
    if (o == 0){
      s_sc[aA] = 2.f / (1.f + __expf(-zA));
      s_sc[aB] = 2.f / (1.f + __expf(-zB));
    }
  }
  __syncthreads();
  {
    float uA = Wf[OFF_BP2 + o], uB = uA;
    const float* w = Wf + OFF_WP2 + o;
    #pragma unroll
    for (int kk = 0; kk < 32; ++kk){
      float wv = w[kk*32];
      uA += s_u1[aA][kk] * wv;
      uB += s_u1[aB][kk] * wv;
    }
    s_in[aA][256 + o] = siluf(uA);
    s_in[aB][256 + o] = siluf(uB);
  }
  __syncthreads();
  {
    float uA = Wf[OFF_BN1 + o], uB = uA;
    const float* w = Wf + OFF_WN1 + o;
    #pragma unroll 8
    for (int kk = 0; kk < 288; ++kk){
      float wv = w[kk*32];
      uA += s_in[aA][kk] * wv;
      uB += s_in[aB][kk] * wv;
    }
    s_un[aA][o] = siluf(uA);
    s_un[aB][o] = siluf(uB);
  }
  __syncthreads();
  {
    float uA = Wf[OFF_BN2 + o], uB = uA;
    const float* w = Wf + OFF_WN2 + o;
    #pragma unroll
    for (int kk = 0; kk < 32; ++kk){
      float wv = w[kk*32];
      uA += s_un[aA][kk] * wv;
      uB += s_un[aB][kk] * wv;
    }
    out[(size_t)(a0 + aA)*32 + o] = s_in[aA][o] + siluf(uA);
    out[(size_t)(a0 + aB)*32 + o] = s_in[aB][o] + siluf(uB);
  }
  if (tid < 48){
    int a = tid / 3, c = tid - a * 3;
    int ga = a0 + a;
    float pv = pvh[(size_t)ga*3 + c] + pvh[30000 + (size_t)ga*3 + c];
    float vup = s_sc[a] * v[ga*3 + c] + pv;
    float xup = x[ga*3 + c] + vup;
    out[N_ATOMS*32 + (size_t)ga*3 + c] = xup;
    out[N_ATOMS*32 + N_ATOMS*3 + (size_t)ga*3 + c] = vup;
  }
}

// ------- fused comb(both halves) + final (fast path) ------------------------
// comb phase: lanes 0..13 each read uint4 (8 cols) per half -> coalesced
// 224B row reads; c = lane*8+j (consistent permutation).
__global__ __launch_bounds__(256) void k_combf(const int* __restrict__ offs,
    const u16* __restrict__ xh0, const u16* __restrict__ xh1,
    const float* __restrict__ dirs, const float* __restrict__ h,
    const float* __restrict__ x, const float* __restrict__ v,
    const float* __restrict__ Wf, const float* __restrict__ hsem,
    float* __restrict__ out){
  __shared__ float s_nsq[16][225];
  __shared__ float s_in[16][289];
  __shared__ float s_u1[16][33];
  __shared__ float s_un[16][33];
  __shared__ float s_sc[16];
  __shared__ float s_pv[16][3];
  int tid = threadIdx.x;
  int a0 = blockIdx.x * 16;
  for (int e = tid; e < 896; e += 256){
    int a = e / 56, q = e - a * 56;
    float4 t = *(const float4*)(hsem + (size_t)(a0 + a) * 224 + q * 4);
    s_in[a][32 + q*4+0] = t.x; s_in[a][32 + q*4+1] = t.y;
    s_in[a][32 + q*4+2] = t.z; s_in[a][32 + q*4+3] = t.w;
  }
  for (int e = tid; e < 128; e += 256){
    int a = e >> 3, q = e & 7;
    float4 t = *(const float4*)(h + (size_t)(a0 + a) * 32 + q * 4);
    s_in[a][q*4+0] = t.x; s_in[a][q*4+1] = t.y;
    s_in[a][q*4+2] = t.z; s_in[a][q*4+3] = t.w;
  }
  {
    int a = tid >> 4, lane = tid & 15;
    int off = offs[a0 + a], end = offs[a0 + a + 1];
    float c0A[8] = {0,0,0,0,0,0,0,0}, c1A[8] = {0,0,0,0,0,0,0,0}, c2A[8] = {0,0,0,0,0,0,0,0};
    float c0B[8] = {0,0,0,0,0,0,0,0}, c1B[8] = {0,0,0,0,0,0,0,0}, c2B[8] = {0,0,0,0,0,0,0,0};
    if (lane < 14){
      for (int s = off; s < end; ++s){
        float d0 = dirs[s*3+0], d1 = dirs[s*3+1], d2 = dirs[s*3+2];
        uint4 ra = *(const uint4*)(xh0 + (size_t)s * 112 + lane * 8);
        uint4 rb = *(const uint4*)(xh1 + (size_t)s * 112 + lane * 8);
        u32 wa[4] = {ra.x, ra.y, ra.z, ra.w};
        u32 wb[4] = {rb.x, rb.y, rb.z, rb.w};
        #pragma unroll
        for (int q = 0; q < 4; ++q){
          float alo, ahi, blo, bhi;
          unpack2(wa[q], alo, ahi); unpack2(wb[q], blo, bhi);
          c0A[2*q]   += d0*alo; c1A[2*q]   += d1*alo; c2A[2*q]   += d2*alo;
          c0A[2*q+1] += d0*ahi; c1A[2*q+1] += d1*ahi; c2A[2*q+1] += d2*ahi;
          c0B[2*q]   += d0*blo; c1B[2*q]   += d1*blo; c2B[2*q]   += d2*blo;
          c0B[2*q+1] += d0*bhi; c1B[2*q+1] += d1*bhi; c2B[2*q+1] += d2*bhi;
        }
      }
    }
    float inv = 1.f / fmaxf((float)(end - off), 1.f);
    float pv0 = 0.f, pv1 = 0.f, pv2 = 0.f;
    if (lane < 14){
      #pragma unroll
      for (int j = 0; j < 8; ++j){
        {
          float m0 = c0A[j]*inv, m1 = c1A[j]*inv, m2 = c2A[j]*inv;
          int c = lane*8 + j;
          s_nsq[a][c] = m0*m0 + m1*m1 + m2*m2;
          float wv = Wf[OFF_WVMIX + c];
          pv0 += wv*m0; pv1 += wv*m1; pv2 += wv*m2;
        }
        {
          float m0 = c0B[j]*inv, m1 = c1B[j]*inv, m2 = c2B[j]*inv;
          int c = 112 + lane*8 + j;
          s_nsq[a][c] = m0*m0 + m1*m1 + m2*m2;
          float wv = Wf[OFF_WVMIX + c];
          pv0 += wv*m0; pv1 += wv*m1; pv2 += wv*m2;
        }
      }
    }
    #pragma unroll
    for (int m = 8; m >= 1; m >>= 1){
      pv0 += __shfl_xor(pv0, m); pv1 += __shfl_xor(pv1, m); pv2 += __shfl_xor(pv2, m);
    }
    if (lane == 0){ s_pv[a][0] = pv0; s_pv[a][1] = pv1; s_pv[a][2] = pv2; }
  }
  __syncthreads();
  int o = tid & 31, g5 = tid >> 5;
  int aA = g5, aB = g5 + 8;
  {
    float uA = Wf[OFF_BP1 + o], uB = uA;
    const float* w = Wf + OFF_WP1 + o;
    #pragma unroll 8
    for (int kk = 0; kk < 224; ++kk){
      float wv = w[kk*32];
      uA += s_nsq[aA][kk] * wv;
      uB += s_nsq[aB][kk] * wv;
    }
    s_u1[aA][o] = siluf(uA);
    s_u1[aB][o] = siluf(uB);
  }
  {
    float gA = Wf[OFF_BV1 + o], gB = gA;
    const float* w = Wf + OFF_WV1 + o;
    #pragma unroll
    for (int kk = 0; kk < 32; ++kk){
      float wv = w[kk*32];
      gA += s_in[aA][kk] * wv;
      gB += s_in[aB][kk] * wv;
    }
    float wv2 = Wf[OFF_WV2 + o];
    float zA = siluf(gA) * wv2, zB = siluf(gB) * wv2;
    #pragma unroll
    for (int m = 16; m >= 1; m >>= 1){
      zA += __shfl_xor(zA, m); zB += __shfl_xor(zB, m);
    }
    if (o == 0){
      s_sc[aA] = 2.f / (1.f + __expf(-zA));
      s_sc[aB] = 2.f / (1.f + __expf(-zB));
    }
  }
  __syncthreads();
  {
    float uA = Wf[OFF_BP2 + o], uB = uA;
    const float* w = Wf + OFF_WP2 + o;
    #pragma unroll
    for (int kk = 0; kk < 32; ++kk){
      float wv = w[kk*32];
      uA += s_u1[aA][kk] * wv;
      uB += s_u1[aB][kk] * wv;
    }
    s_in[aA][256 + o] = siluf(uA);
    s_in[aB][256 + o] = siluf(uB);
  }
  __syncthreads();
  {
    float uA = Wf[OFF_BN1 + o], uB = uA;
    const float* w = Wf + OFF_WN1 + o;
    #pragma unroll 8
    for (int kk = 0; kk < 288; ++kk){
      float wv = w[kk*32];
      uA += s_in[aA][kk] * wv;
      uB += s_in[aB][kk] * wv;
    }
    s_un[aA][o] = siluf(uA);
    s_un[aB][o] = siluf(uB);
  }
  __syncthreads();
  {
    float uA = Wf[OFF_BN2 + o], uB = uA;
    const float* w = Wf + OFF_WN2 + o;
    #pragma unroll
    for (int kk = 0; kk < 32; ++kk){
      float wv = w[kk*32];
      uA += s_un[aA][kk] * wv;
      uB += s_un[aB][kk] * wv;
    }
    out[(size_t)(a0 + aA)*32 + o] = s_in[aA][o] + siluf(uA);
    out[(size_t)(a0 + aB)*32 + o] = s_in[aB][o] + siluf(uB);
  }
  if (tid < 48){
    int a = tid / 3, c = tid - a * 3;
    int ga = a0 + a;
    float vup = s_sc[a] * v[ga*3 + c] + s_pv[a][c];
    float xup = x[ga*3 + c] + vup;
    out[N_ATOMS*32 + (size_t)ga*3 + c] = xup;
    out[N_ATOMS*32 + N_ATOMS*3 + (size_t)ga*3 + c] = vup;
  }
}

// ---------------- workspace layout ----------------
static constexpr size_t al256(size_t x){ return (x + 255) & ~(size_t)255; }
static constexpr size_t WS_FLAGS   = 0;
static constexpr size_t WS_COUNTS  = al256(WS_FLAGS + 8);
static constexpr size_t WS_OFFSETS = al256(WS_COUNTS + (size_t)N_ATOMS * 4);
static constexpr size_t WS_CURSOR  = al256(WS_OFFSETS + (size_t)(N_ATOMS + 1) * 4);
static constexpr size_t WS_PERM    = al256(WS_CURSOR + (size_t)N_ATOMS * 4);   // isrt
static constexpr size_t WS_PLI     = al256(WS_PERM + (size_t)P_PAIRS * 4);
static constexpr size_t WS_HF      = al256(WS_PLI + (size_t)2 * P_PAIRS * 4);
static constexpr size_t WS_XF      = al256(WS_HF + (size_t)N_ATOMS * 32 * 4);
static constexpr size_t WS_VF      = al256(WS_XF + (size_t)N_ATOMS * 3 * 4);
static constexpr size_t WS_WF      = al256(WS_VF + (size_t)N_ATOMS * 3 * 4);
static constexpr size_t WS_WT      = al256(WS_WF + (size_t)WF_TOTAL * 4);
static constexpr size_t WS_EDGE    = al256(WS_WT + (size_t)224 * 224 * 2);
static constexpr size_t WS_ATTS    = al256(WS_EDGE + (size_t)P_PAIRS * 32 * 2);
static constexpr size_t WS_DIRS    = al256(WS_ATTS + (size_t)P_PAIRS * 7 * 4);
static constexpr size_t WS_LOGITS  = al256(WS_DIRS + (size_t)P_PAIRS * 3 * 4);
// SMALL (fallback) layout:
static constexpr size_t WS_PREI    = al256(WS_LOGITS + (size_t)P_PAIRS * 7 * 4);
static constexpr size_t WS_PREJ    = al256(WS_PREI + (size_t)N_ATOMS * 88 * 2);
static constexpr size_t WS_HSEM    = WS_LOGITS + 4480000;
static constexpr size_t WS_XH      = WS_HSEM + (size_t)N_ATOMS * 224 * 4;
static constexpr size_t WS_NSQ     = WS_XH + (size_t)P_PAIRS * 112 * 2;
static constexpr size_t WS_PVH     = WS_NSQ + (size_t)N_ATOMS * 224 * 4;
static constexpr size_t WS_JSRT    = al256(WS_PVH + (size_t)2 * 30000 * 4);
static constexpr size_t WS_BPK     = al256(WS_JSRT + (size_t)P_PAIRS * 4);
static constexpr size_t WS_END     = WS_BPK + 3584 * 2;
// BIG (fast path) layout: two xhalf buffers, no nsq/pvh.
static constexpr size_t WB_XH0     = WS_XH;
static constexpr size_t WB_XH1     = WB_XH0 + (size_t)P_PAIRS * 112 * 2;
static constexpr size_t WB_JSRT    = al256(WB_XH1 + (size_t)P_PAIRS * 112 * 2);
static constexpr size_t WB_BPK     = al256(WB_JSRT + (size_t)P_PAIRS * 4);
static constexpr size_t WB_END     = WB_BPK + 3584 * 2;
static_assert(WS_PREJ + (size_t)N_ATOMS * 88 * 2 <= WS_XH, "pre tables before xhalf");
static_assert(WS_END <= WS_LOGITS + (size_t)P_PAIRS * 224 * 2, "fallback within proven footprint");
static_assert(WS_HSEM % 256 == 0 && WS_XH % 256 == 0 && WS_NSQ % 256 == 0 && WS_PVH % 256 == 0, "alignment");
static_assert(WB_XH1 % 256 == 0, "alignment");

extern "C" void kernel_launch(void* const* d_in, const int* in_sizes, int n_in,
                              void* d_out, int out_size, void* d_ws, size_t ws_size,
                              hipStream_t stream){
  (void)in_sizes; (void)n_in;
  if (out_size != 380000 || ws_size < WS_END){
    k_code<<<1, 64, 0, stream>>>((float*)d_out, 14000.f);
    return;
  }
  char* ws = (char*)d_ws;
  int*   counts = (int*)(ws + WS_COUNTS);
  int*   offs   = (int*)(ws + WS_OFFSETS);
  int*   cursor = (int*)(ws + WS_CURSOR);
  int*   isrt   = (int*)(ws + WS_PERM);
  int*   pli    = (int*)(ws + WS_PLI);
  float* hf     = (float*)(ws + WS_HF);
  float* xf     = (float*)(ws + WS_XF);
  float* vf     = (float*)(ws + WS_VF);
  float* Wf     = (float*)(ws + WS_WF);
  u16*   wT     = (u16*)(ws + WS_WT);
  u16*   edge   = (u16*)(ws + WS_EDGE);
  float* atts   = (float*)(ws + WS_ATTS);
  float* dirs   = (float*)(ws + WS_DIRS);
  float* logits = (float*)(ws + WS_LOGITS);
  u16*   prei   = (u16*)(ws + WS_PREI);
  u16*   prej   = (u16*)(ws + WS_PREJ);
  float* hsem   = (float*)(ws + WS_HSEM);

  bool big = (ws_size >= WB_END);
  u16*   xh0  = (u16*)(ws + WB_XH0);
  u16*   xh1  = big ? (u16*)(ws + WB_XH1) : xh0;
  int*   jsrt = big ? (int*)(ws + WB_JSRT) : (int*)(ws + WS_JSRT);
  u16*   bpk  = big ? (u16*)(ws + WB_BPK) : (u16*)(ws + WS_BPK);
  float* nsq  = (float*)(ws + WS_NSQ);
  float* pvh  = (float*)(ws + WS_PVH);

  hipMemsetAsync(counts, 0, (size_t)N_ATOMS * 4, stream);
  k_prep<<<NBP_HIST, 256, 0, stream>>>(d_in[0], d_in[1], d_in[2], d_in[3],
      d_in[4],  d_in[5],  d_in[6],  d_in[7],  d_in[8],  d_in[9],  d_in[10], d_in[11],
      d_in[12], d_in[13], d_in[14], d_in[15], d_in[16], d_in[17], d_in[18], d_in[19],
      d_in[20], d_in[21], d_in[22], d_in[24], d_in[23],
      hf, xf, vf, pli, Wf, wT, bpk, counts);
  k_atomscan<<<626, 256, 0, stream>>>(hf, Wf, prei, prej, counts, offs, cursor);
  k_scatter<<<P_PAIRS / 256, 256, 0, stream>>>(pli, cursor, isrt, jsrt);
  k_pairm<<<P_PAIRS / 128, 256, 0, stream>>>(xf, Wf, prei, prej, isrt, jsrt, bpk, edge, logits, dirs);
  k_att<<<N_ATOMS / 16, 256, 0, stream>>>(offs, logits, edge, atts, hsem);
  if (big){
    k_gemm3f<<<P_PAIRS / 64, 256, 0, stream>>>(edge, atts, wT, xh0, xh1);
    k_combf<<<625, 256, 0, stream>>>(offs, xh0, xh1, dirs, hf, xf, vf, Wf, hsem, (float*)d_out);
  } else {
    k_gemm3<<<P_PAIRS / 64, 256, 0, stream>>>(edge, atts, wT, xh0, xh0, 0);
    k_comb<<<N_ATOMS / 16, 256, 0, stream>>>(offs, xh0, dirs, Wf, 0, nsq, pvh);
    k_gemm3<<<P_PAIRS / 64, 256, 0, stream>>>(edge, atts, wT, xh0, xh0, 1);
    k_comb<<<N_ATOMS / 16, 256, 0, stream>>>(offs, xh0, dirs, Wf, 1, nsq, pvh);
    k_final4<<<625, 256, 0, stream>>>(hf, xf, vf, Wf, hsem, nsq, pvh, (float*)d_out);
  }
}

// Round 16
// 312.603 us; speedup vs baseline: 1.6982x; 1.6982x over previous
//
#include <hip/hip_runtime.h>

typedef unsigned short u16;
typedef unsigned int u32;
typedef __attribute__((ext_vector_type(8))) short short8;
typedef __attribute__((ext_vector_type(4))) float floatx4;

#define P_PAIRS 160000
#define N_ATOMS 10000

#define OFF_WMLP  0      // stored TRANSPOSED: [50][64], (o,k) at o*64+k
#define OFF_BMLP  3200
#define OFF_WE1   3250
#define OFF_BE1   6930
#define OFF_WE2   6962
#define OFF_BE2   7986
#define OFF_WATT  8018
#define OFF_BATT  8242
#define OFF_WN1   8249
#define OFF_BN1   17465
#define OFF_WN2   17497
#define OFF_BN2   18521
#define OFF_WP1   18553
#define OFF_BP1   25721
#define OFF_WP2   25753
#define OFF_BP2   26777
#define OFF_WV1   26809
#define OFF_BV1   27833
#define OFF_WV2   27865
#define OFF_WVMIX 27897
#define WF_TOTAL  28121

__device__ __forceinline__ float b2f(u16 u){ return __uint_as_float(((u32)u) << 16); }
__device__ __forceinline__ u16 f2b(float f){
  u32 u = __float_as_uint(f);
  u32 r = (u + 0x7FFFu + ((u >> 16) & 1u)) >> 16;
  return (u16)r;
}
__device__ __forceinline__ void unpack2(u32 p, float& lo, float& hi){
  lo = __uint_as_float(p << 16);
  hi = __uint_as_float(p & 0xFFFF0000u);
}
__device__ __forceinline__ float siluf(float v){ return v / (1.f + __expf(-v)); }
__device__ __forceinline__ float ldw(const void* p, int o, int bf){
  return bf ? b2f(((const u16*)p)[o]) : ((const float*)p)[o];
}

__global__ void k_code(float* out, float code){
  if (threadIdx.x == 0 && blockIdx.x == 0) out[0] = code;
}

// per-block dtype detection (wave 0 ballot)
__device__ __forceinline__ void detect_flags(const u32* hw, const u32* plw, int* s_fl){
  int tid = threadIdx.x;
  if (tid < 64){
    u32 e = (hw[tid] >> 7) & 0xFFu;
    unsigned long long m1 = __ballot(e >= 100u && e <= 140u);
    unsigned long long m2 = __ballot(plw[2*tid+1] == 0u);
    if (tid == 0){
      s_fl[0] = (__popcll(m1) >= 48) ? 1 : 0;
      s_fl[1] = (__popcll(m2) >= 60) ? 1 : 0;
    }
  }
  __syncthreads();
}

// ------------- fused preprocessing: norm + convert + transpose + bpk + hist -
#define NBP_NORM 2735
#define NBP_CONV (NBP_NORM + 110)
#define NBP_TRAN (NBP_CONV + 196)
#define NBP_PB   (NBP_TRAN + 14)
#define NBP_HIST (NBP_PB + 625)

__global__ void k_prep(const void* __restrict__ h_raw, const void* __restrict__ x_raw,
    const void* __restrict__ v_raw, const void* __restrict__ pl_raw,
    const void* w_mlp, const void* b_mlp, const void* w_e1, const void* b_e1,
    const void* w_e2, const void* b_e2, const void* w_att, const void* b_att,
    const void* w_n1, const void* b_n1, const void* w_n2, const void* b_n2,
    const void* w_p1, const void* b_p1, const void* w_p2, const void* b_p2,
    const void* w_v1, const void* b_v1, const void* w_v2, const void* w_vmix,
    const void* wx,
    float* __restrict__ hf, float* __restrict__ xf, float* __restrict__ vf,
    int* __restrict__ pli, float* __restrict__ Wf, u16* __restrict__ wT,
    u16* __restrict__ bpk, int* __restrict__ counts){
  __shared__ int s_fl[2];
  detect_flags((const u32*)h_raw, (const u32*)pl_raw, s_fl);
  int bf = s_fl[0], i64 = s_fl[1];
  int bid = blockIdx.x, tid = threadIdx.x;
  if (bid < NBP_NORM){
    int t = bid * 256 + tid;
    if (t < 320000){
      hf[t] = ldw(h_raw, t, bf);
    } else if (t < 350000){
      int i = t - 320000; xf[i] = ldw(x_raw, i, bf);
    } else if (t < 380000){
      int i = t - 350000; vf[i] = ldw(v_raw, i, bf);
    } else if (t < 700000){
      int k = t - 380000;
      const int* p32 = (const int*)pl_raw;
      pli[k] = i64 ? p32[2*(size_t)k] : p32[k];
    }
  } else if (bid < NBP_CONV){
    int t = (bid - NBP_NORM) * 256 + tid;
    if (t >= WF_TOTAL) return;
    if (t < 3200){
      int k = t / 50, o = t - k * 50;
      Wf[OFF_WMLP + o * 64 + k] = ldw(w_mlp, t, bf);
      return;
    }
    const void* src; int o;
    if      (t < 3250)  { src = b_mlp;  o = t - 3200; }
    else if (t < 6930)  { src = w_e1;   o = t - 3250; }
    else if (t < 6962)  { src = b_e1;   o = t - 6930; }
    else if (t < 7986)  { src = w_e2;   o = t - 6962; }
    else if (t < 8018)  { src = b_e2;   o = t - 7986; }
    else if (t < 8242)  { src = w_att;  o = t - 8018; }
    else if (t < 8249)  { src = b_att;  o = t - 8242; }
    else if (t < 17465) { src = w_n1;   o = t - 8249; }
    else if (t < 17497) { src = b_n1;   o = t - 17465; }
    else if (t < 18521) { src = w_n2;   o = t - 17497; }
    else if (t < 18553) { src = b_n2;   o = t - 18521; }
    else if (t < 25721) { src = w_p1;   o = t - 18553; }
    else if (t < 25753) { src = b_p1;   o = t - 25721; }
    else if (t < 26777) { src = w_p2;   o = t - 25753; }
    else if (t < 26809) { src = b_p2;   o = t - 26777; }
    else if (t < 27833) { src = w_v1;   o = t - 26809; }
    else if (t < 27865) { src = b_v1;   o = t - 27833; }
    else if (t < 27897) { src = w_v2;   o = t - 27865; }
    else                { src = w_vmix; o = t - 27897; }
    Wf[t] = ldw(src, o, bf);
  } else if (bid < NBP_TRAN){
    int t = (bid - NBP_CONV) * 256 + tid;
    if (t >= 224 * 224) return;
    int n = t / 224, k = t - n * 224;
    wT[t] = f2b(ldw(wx, k * 224 + n, bf));
  } else if (bid < NBP_PB){
    // bpk: B1T [32][64] | B2T [32][32] | B3T [16][32]  (bf16, from RAW weights)
    int t = (bid - NBP_TRAN) * 256 + tid;
    if (t >= 3584) return;
    float v = 0.f;
    if (t < 2048){
      int n = t >> 6, k = t & 63;
      if (k < 50)       v = ldw(w_e1, (64 + k) * 32 + n, bf);
      else if (k == 50) v = ldw(w_e1, 114 * 32 + n, bf);
    } else if (t < 3072){
      int e = t - 2048; int n = e >> 5, k = e & 31;
      v = ldw(w_e2, k * 32 + n, bf);
    } else {
      int e = t - 3072; int n = e >> 5, k = e & 31;
      if (n < 7) v = ldw(w_att, k * 7 + n, bf);
    }
    bpk[t] = f2b(v);
  } else {
    int p = (bid - NBP_PB) * 256 + tid;     // hist from raw pairlist
    const int* p32 = (const int*)pl_raw;
    int i = i64 ? p32[2*(size_t)p] : p32[p];
    atomicAdd(&counts[i], 1);
  }
}

// ---------- fused: per-atom projections (625 fat blocks) + scan (1 block) ---
__global__ void k_atomscan(const float* __restrict__ hf, const float* __restrict__ Wf,
    u16* __restrict__ prei, u16* __restrict__ prej,
    const int* __restrict__ counts, int* __restrict__ offs, int* __restrict__ cursor){
  __shared__ float hs[16][33];
  __shared__ int part[256];
  int tid = threadIdx.x;
  if (blockIdx.x < 625){
    int a0 = blockIdx.x * 16;
    for (int e = tid; e < 512; e += 256){
      int a = e >> 5, k = e & 31;
      hs[a][k] = hf[(size_t)(a0 + a) * 32 + k];
    }
    __syncthreads();
    for (int e = tid; e < 800; e += 256){
      int a = e / 50, r = e - a * 50;
      const float* wm = Wf + OFF_WMLP + r * 64;
      float acc = Wf[OFF_BMLP + r];
      #pragma unroll
      for (int k = 0; k < 32; ++k) acc += hs[a][k] * wm[k];
      prei[(size_t)(a0 + a) * 88 + 32 + r] = f2b(acc);
    }
    for (int e = tid; e < 800; e += 256){
      int a = e / 50, r = e - a * 50;
      const float* wm = Wf + OFF_WMLP + r * 64 + 32;
      float acc = 0.f;
      #pragma unroll
      for (int k = 0; k < 32; ++k) acc += hs[a][k] * wm[k];
      prej[(size_t)(a0 + a) * 88 + 32 + r] = f2b(acc);
    }
    for (int e = tid; e < 512; e += 256){
      int a = e >> 5, o = e & 31;
      float acc = Wf[OFF_BE1 + o];
      #pragma unroll
      for (int k = 0; k < 32; ++k) acc += hs[a][k] * Wf[OFF_WE1 + k * 32 + o];
      prei[(size_t)(a0 + a) * 88 + o] = f2b(acc);
    }
    for (int e = tid; e < 512; e += 256){
      int a = e >> 5, o = e & 31;
      float acc = 0.f;
      #pragma unroll
      for (int k = 0; k < 32; ++k) acc += hs[a][k] * Wf[OFF_WE1 + (32 + k) * 32 + o];
      prej[(size_t)(a0 + a) * 88 + o] = f2b(acc);
    }
  } else {
    int sum = 0;
    for (int k = 0; k < 40; ++k){
      int idx = tid * 40 + k;
      if (idx < N_ATOMS) sum += counts[idx];
    }
    part[tid] = sum;
    __syncthreads();
    if (tid == 0){
      int run = 0;
      for (int q = 0; q < 256; ++q){ int tmp = part[q]; part[q] = run; run += tmp; }
    }
    __syncthreads();
    int run = part[tid];
    for (int k = 0; k < 40; ++k){
      int idx = tid * 40 + k;
      if (idx < N_ATOMS){ offs[idx] = run; cursor[idx] = run; run += counts[idx]; }
    }
    if (tid == 0) offs[N_ATOMS] = P_PAIRS;
  }
}

__global__ void k_scatter(const int* __restrict__ pl, int* __restrict__ cursor,
                          int* __restrict__ isrt, int* __restrict__ jsrt){
  int p = blockIdx.x * 256 + threadIdx.x;
  int i = pl[p];
  int pos = atomicAdd(&cursor[i], 1);
  isrt[pos] = i;
  jsrt[pos] = pl[P_PAIRS + p];
}

// ------- per-pair edge model via MFMA: 128 pairs/block, 4 waves -------------
#define PM_UB   0
#define PM_TB   16384
#define PM_DD   30720
#define PM_A1   31232
#define PM_B1   49664
#define PM_A2   54272
#define PM_B2   64512
#define PM_B3   67072
#define PM_TOT  68352

__global__ __launch_bounds__(256) void k_pairm(const float* __restrict__ x,
    const float* __restrict__ Wf, const u16* __restrict__ prei, const u16* __restrict__ prej,
    const int* __restrict__ isrt, const int* __restrict__ jsrt, const u16* __restrict__ bpk,
    u16* __restrict__ edge, float* __restrict__ logits, float* __restrict__ dirs){
  __shared__ __attribute__((aligned(16))) char smem[PM_TOT];
  float* UB = (float*)(smem + PM_UB);
  u16*   TB = (u16*)(smem + PM_TB);
  float* DD = (float*)(smem + PM_DD);
  u16*   A1 = (u16*)(smem + PM_A1);
  u16*   B1 = (u16*)(smem + PM_B1);
  u16*   A2 = (u16*)(smem + PM_A2);
  u16*   B2 = (u16*)(smem + PM_B2);
  u16*   B3 = (u16*)(smem + PM_B3);
  int tid = threadIdx.x;
  int wave = tid >> 6, lane = tid & 63, l15 = lane & 15, quad = lane >> 4;
  int row0 = blockIdx.x * 128;

  if (tid < 128){
    int s = row0 + tid;
    int i = isrt[s], j = jsrt[s];
    float r0 = x[j*3+0] - x[i*3+0];
    float r1 = x[j*3+1] - x[i*3+1];
    float r2 = x[j*3+2] - x[i*3+2];
    float d = sqrtf(r0*r0 + r1*r1 + r2*r2);
    float rinv = 1.f / (d + 1e-5f);
    dirs[s*3+0] = r0*rinv; dirs[s*3+1] = r1*rinv; dirs[s*3+2] = r2*rinv;
    DD[tid] = d;
    const uint4* pi4 = (const uint4*)(prei + (size_t)i * 88);
    const uint4* pj4 = (const uint4*)(prej + (size_t)j * 88);
    float* ub = UB + tid * 32;
    #pragma unroll
    for (int q = 0; q < 4; ++q){
      uint4 a4 = pi4[q], b4 = pj4[q];
      u32 pa[4] = {a4.x, a4.y, a4.z, a4.w};
      u32 pb[4] = {b4.x, b4.y, b4.z, b4.w};
      #pragma unroll
      for (int w2 = 0; w2 < 4; ++w2){
        float al, ah, bl, bh;
        unpack2(pa[w2], al, ah); unpack2(pb[w2], bl, bh);
        ub[q*8 + w2*2]     = al + bl;
        ub[q*8 + w2*2 + 1] = ah + bh;
      }
    }
    u32* tb = (u32*)TB + tid * 28;
    #pragma unroll
    for (int q = 0; q < 7; ++q){
      uint4 a4 = pi4[4+q], b4 = pj4[4+q];
      u32 pa[4] = {a4.x, a4.y, a4.z, a4.w};
      u32 pb[4] = {b4.x, b4.y, b4.z, b4.w};
      #pragma unroll
      for (int w2 = 0; w2 < 4; ++w2){
        float al, ah, bl, bh;
        unpack2(pa[w2], al, ah); unpack2(pb[w2], bl, bh);
        tb[q*4 + w2] = (u32)f2b(al + bl) | ((u32)f2b(ah + bh) << 16);
      }
    }
  } else {
    int t2 = tid - 128;
    const u32* src = (const u32*)bpk;
    for (int e = t2; e < 1024; e += 128){         // B1T [32][64] -> stride 36 u32
      int n = e >> 5, kp = e & 31;
      ((u32*)B1)[n*36 + kp] = src[e];
    }
    for (int e = t2; e < 512; e += 128){          // B2T [32][32] -> stride 20 u32
      int n = e >> 4, kp = e & 15;
      ((u32*)B2)[n*20 + kp] = src[1024 + e];
    }
    for (int e = t2; e < 256; e += 128){          // B3T [16][32] -> stride 20 u32
      int n = e >> 4, kp = e & 15;
      ((u32*)B3)[n*20 + kp] = src[1536 + e];
    }
  }
  __syncthreads();
  // A1 [128][72-stride]: cols 0..49 filt, col 50 = d, 51..63 = 0
  for (int e = tid; e < 4096; e += 256){
    int r = e >> 5, kp = e & 31;
    int k0 = kp * 2, k1 = k0 + 1;
    float d = DD[r];
    float v0 = 0.f, v1 = 0.f;
    if (k0 < 50){
      float t0 = b2f(TB[r*56 + k0]);
      float c0 = (float)k0 * (5.f/49.f), dd0 = d - c0;
      v0 = t0 * __expf(-10.f * dd0 * dd0);
    } else if (k0 == 50) v0 = d;
    if (k1 < 50){
      float t1 = b2f(TB[r*56 + k1]);
      float c1 = (float)k1 * (5.f/49.f), dd1 = d - c1;
      v1 = t1 * __expf(-10.f * dd1 * dd1);
    }
    ((u32*)A1)[r*36 + kp] = (u32)f2b(v0) | ((u32)f2b(v1) << 16);
  }
  __syncthreads();
  // u = A1 @ B1 + UB  (M=128 N=32 K=64)
  floatx4 au[2][2];
  #pragma unroll
  for (int mt = 0; mt < 2; ++mt)
    #pragma unroll
    for (int nt = 0; nt < 2; ++nt) au[mt][nt] = (floatx4){0.f,0.f,0.f,0.f};
  #pragma unroll
  for (int ks = 0; ks < 2; ++ks){
    int kk = ks * 32;
    short8 a0 = *(const short8*)(A1 + (wave*32 + l15)*72 + kk + quad*8);
    short8 a1 = *(const short8*)(A1 + (wave*32 + 16 + l15)*72 + kk + quad*8);
    #pragma unroll
    for (int nt = 0; nt < 2; ++nt){
      short8 b = *(const short8*)(B1 + (nt*16 + l15)*72 + kk + quad*8);
      au[0][nt] = __builtin_amdgcn_mfma_f32_16x16x32_bf16(a0, b, au[0][nt], 0, 0, 0);
      au[1][nt] = __builtin_amdgcn_mfma_f32_16x16x32_bf16(a1, b, au[1][nt], 0, 0, 0);
    }
  }
  #pragma unroll
  for (int mt = 0; mt < 2; ++mt)
    #pragma unroll
    for (int nt = 0; nt < 2; ++nt)
      #pragma unroll
      for (int reg = 0; reg < 4; ++reg){
        int r = wave*32 + mt*16 + quad*4 + reg;
        int c = nt*16 + l15;
        float uval = au[mt][nt][reg] + UB[r*32 + c];
        A2[r*40 + c] = f2b(siluf(uval));
      }
  __syncthreads();
  // eg = A2 @ B2 (M=128 N=32 K=32)
  floatx4 ae[2][2];
  #pragma unroll
  for (int mt = 0; mt < 2; ++mt)
    #pragma unroll
    for (int nt = 0; nt < 2; ++nt) ae[mt][nt] = (floatx4){0.f,0.f,0.f,0.f};
  {
    short8 a0 = *(const short8*)(A2 + (wave*32 + l15)*40 + quad*8);
    short8 a1 = *(const short8*)(A2 + (wave*32 + 16 + l15)*40 + quad*8);
    #pragma unroll
    for (int nt = 0; nt < 2; ++nt){
      short8 b = *(const short8*)(B2 + (nt*16 + l15)*40 + quad*8);
      ae[0][nt] = __builtin_amdgcn_mfma_f32_16x16x32_bf16(a0, b, ae[0][nt], 0, 0, 0);
      ae[1][nt] = __builtin_amdgcn_mfma_f32_16x16x32_bf16(a1, b, ae[1][nt], 0, 0, 0);
    }
  }
  __syncthreads();    // all A2 (silu-u) reads done before overwrite with eg
  #pragma unroll
  for (int mt = 0; mt < 2; ++mt)
    #pragma unroll
    for (int nt = 0; nt < 2; ++nt)
      #pragma unroll
      for (int reg = 0; reg < 4; ++reg){
        int r = wave*32 + mt*16 + quad*4 + reg;
        int c = nt*16 + l15;
        float ev = ae[mt][nt][reg] + Wf[OFF_BE2 + c];
        A2[r*40 + c] = f2b(ev);
      }
  __syncthreads();
  // edge copy-out (coalesced)
  {
    int r = tid >> 1, p = tid & 1;
    const uint4* srcp = (const uint4*)(A2 + r*40 + p*16);
    uint4* dstp = (uint4*)(edge + (size_t)(row0 + r)*32 + p*16);
    dstp[0] = srcp[0]; dstp[1] = srcp[1];
  }
  // logits = celu(A2 @ B3 + batt)  (N=16, 7 used)
  floatx4 al_[2];
  al_[0] = (floatx4){0.f,0.f,0.f,0.f};
  al_[1] = (floatx4){0.f,0.f,0.f,0.f};
  {
    short8 a0 = *(const short8*)(A2 + (wave*32 + l15)*40 + quad*8);
    short8 a1 = *(const short8*)(A2 + (wave*32 + 16 + l15)*40 + quad*8);
    short8 b = *(const short8*)(B3 + l15*40 + quad*8);
    al_[0] = __builtin_amdgcn_mfma_f32_16x16x32_bf16(a0, b, al_[0], 0, 0, 0);
    al_[1] = __builtin_amdgcn_mfma_f32_16x16x32_bf16(a1, b, al_[1], 0, 0, 0);
  }
  if (l15 < 7){
    float ba = Wf[OFF_BATT + l15];
    #pragma unroll
    for (int mt = 0; mt < 2; ++mt)
      #pragma unroll
      for (int reg = 0; reg < 4; ++reg){
        int r = wave*32 + mt*16 + quad*4 + reg;
        float vv = al_[mt][reg] + ba;
        float cl = vv > 0.f ? vv : 2.f * expm1f(0.5f * vv);
        logits[(size_t)(row0 + r)*7 + l15] = cl;
      }
  }
}

// -------- segment softmax + hsem accumulation (16-lane group per atom) ------
__global__ __launch_bounds__(256) void k_att(const int* __restrict__ offs,
    const float* __restrict__ logits, const u16* __restrict__ edge,
    float* __restrict__ atts, float* __restrict__ hsem){
  int a = blockIdx.x * 16 + (threadIdx.x >> 4);   // N = 625*16
  int lane = threadIdx.x & 15;
  int off = offs[a], end = offs[a+1];
  float m[7];
  #pragma unroll
  for (int hh = 0; hh < 7; ++hh) m[hh] = -1e30f;
  for (int s = off + lane; s < end; s += 16){
    #pragma unroll
    for (int hh = 0; hh < 7; ++hh) m[hh] = fmaxf(m[hh], logits[s*7+hh]);
  }
  #pragma unroll
  for (int hh = 0; hh < 7; ++hh){
    float v = m[hh];
    #pragma unroll
    for (int msk = 8; msk >= 1; msk >>= 1) v = fmaxf(v, __shfl_xor(v, msk));
    m[hh] = v;
  }
  float sm[7] = {0,0,0,0,0,0,0};
  for (int s = off + lane; s < end; s += 16){
    #pragma unroll
    for (int hh = 0; hh < 7; ++hh){
      float e = __expf(logits[s*7+hh] - m[hh]);
      sm[hh] += e;
      atts[s*7+hh] = e;
    }
  }
  #pragma unroll
  for (int hh = 0; hh < 7; ++hh){
    float v = sm[hh];
    #pragma unroll
    for (int msk = 8; msk >= 1; msk >>= 1) v += __shfl_xor(v, msk);
    sm[hh] = 1.f / v;
  }
  for (int s = off + lane; s < end; s += 16){
    #pragma unroll
    for (int hh = 0; hh < 7; ++hh) atts[s*7+hh] *= sm[hh];
  }
  __syncthreads();
  float acc[14] = {0,0,0,0,0,0,0,0,0,0,0,0,0,0};
  for (int s = off; s < end; ++s){
    u32 ev = *(const u32*)(edge + (size_t)s * 32 + lane * 2);
    float e0 = b2f((u16)(ev & 0xFFFFu));
    float e1 = b2f((u16)(ev >> 16));
    const float* ap = atts + (size_t)s * 7;
    #pragma unroll
    for (int hh = 0; hh < 7; ++hh){
      float at = ap[hh];
      acc[hh]     += e0 * at;
      acc[7 + hh] += e1 * at;
    }
  }
  float* hp = hsem + (size_t)a * 224 + lane * 14;
  #pragma unroll
  for (int jj = 0; jj < 14; ++jj) hp[jj] = acc[jj];
}

// -------- MFMA GEMM (round-11 proven): M=64, half-width, LDS-B --------------
// mode >= 0: single half (grid 2500). mode < 0: both halves (grid 5000,
// half = bid&1, row0 = (bid>>1)*64) — paired blocks share edge/atts (L2).
#define G_BS   29696
#define G_EL   29696
#define G_AL   (29696 + 4608)
#define G_TOT  38656

__global__ __launch_bounds__(256, 4) void k_gemm3(const u16* __restrict__ edge,
    const float* __restrict__ atts, const u16* __restrict__ BT,
    u16* __restrict__ xh0, u16* __restrict__ xh1, int mode){
  __shared__ __attribute__((aligned(16))) char smem[G_TOT];
  u16*   As  = (u16*)smem;                 // stride 232 u16 (116 u32)
  u16*   xth = (u16*)smem;                 // stride 120 u16, overlays As after MFMA
  u16*   Bs  = (u16*)(smem + G_BS);        // stride 40 u16
  u16*   eL  = (u16*)(smem + G_EL);        // stride 36 u16 (overlay, dead after pack)
  float* aL  = (float*)(smem + G_AL);      // stride 7 floats (overlay)
  int tid = threadIdx.x;
  int wave = tid >> 6, lane = tid & 63, l15 = lane & 15, quad = lane >> 4;
  int bid = blockIdx.x;
  int half, rblk;
  if (mode < 0){ half = bid & 1; rblk = bid >> 1; }
  else         { half = mode;    rblk = bid; }
  u16* xhalf = half ? xh1 : xh0;
  int row0 = rblk * 64;
  int nbase = half * 112;

  // stage edge rows (padded stride 36) + atts
  for (int e = tid; e < 512; e += 256){
    int r = e >> 3, q = e & 7;
    *(uint2*)(eL + r*36 + q*4) = *(const uint2*)(edge + (size_t)(row0 + r)*32 + q*4);
  }
  for (int e = tid; e < 448; e += 256) aL[e] = atts[(size_t)row0*7 + e];
  floatx4 acc[7];
  #pragma unroll
  for (int nt = 0; nt < 7; ++nt) acc[nt] = (floatx4){0.f, 0.f, 0.f, 0.f};
  __syncthreads();

  // pack full-K A-tile once: thread t -> row t>>2, quarter (t&3)*56 cols
  {
    int pr = tid >> 2, q = tid & 3;
    u32* asw = (u32*)As + pr*116 + q*28;
    const u16* er = eL + pr*36 + q*8;
    const float* ar = aL + pr*7;
    float av[7];
    #pragma unroll
    for (int hh = 0; hh < 7; ++hh) av[hh] = ar[hh];
    #pragma unroll
    for (int fo2 = 0; fo2 < 4; ++fo2){
      float e0 = b2f(er[2*fo2]);
      float e1 = b2f(er[2*fo2+1]);
      u16 w[14];
      #pragma unroll
      for (int hh = 0; hh < 7; ++hh){
        w[hh]   = f2b(e0 * av[hh]);
        w[7+hh] = f2b(e1 * av[hh]);
      }
      #pragma unroll
      for (int k = 0; k < 7; ++k)
        asw[fo2*7 + k] = (u32)w[2*k] | ((u32)w[2*k+1] << 16);
    }
  }
  __syncthreads();          // As ready; eL/aL dead -> Bs usable

  for (int kt = 0; kt < 7; ++kt){
    for (int e = tid; e < 448; e += 256){
      int r = e >> 2, q = e & 3;
      *(uint4*)(Bs + r*40 + q*8) = *(const uint4*)(BT + (size_t)(nbase + r)*224 + kt*32 + q*8);
    }
    __syncthreads();
    int kk = kt * 32;
    short8 a0 = *(const short8*)(As + (wave*16 + l15)*232 + kk + quad*8);
    #pragma unroll
    for (int nt = 0; nt < 7; ++nt){
      short8 b = *(const short8*)(Bs + (nt*16 + l15)*40 + quad*8);
      acc[nt] = __builtin_amdgcn_mfma_f32_16x16x32_bf16(a0, b, acc[nt], 0, 0, 0);
    }
    __syncthreads();        // MFMA reads done before next stage overwrites Bs
  }

  // tanh epilogue -> xth (stride 120), wave-local rows
  #pragma unroll
  for (int nt = 0; nt < 7; ++nt)
    #pragma unroll
    for (int reg = 0; reg < 4; ++reg){
      int r = wave*16 + quad*4 + reg;
      int c = nt*16 + l15;
      float vv = acc[nt][reg];
      vv = fminf(fmaxf(vv, -15.f), 15.f);
      float e2 = __expf(2.f * vv);
      xth[r*120 + c] = f2b((e2 - 1.f) / (e2 + 1.f));
    }
  __syncthreads();
  for (int e = tid; e < 896; e += 256){
    int r = e / 14, w = e - r * 14;
    *(uint4*)(xhalf + (size_t)(row0 + r)*112 + w*8) = *(const uint4*)(xth + r*120 + w*8);
  }
}

// -------- atom-centric comb reduction (fallback path) -----------------------
__global__ __launch_bounds__(256) void k_comb(const int* __restrict__ offs,
    const u16* __restrict__ xhalf, const float* __restrict__ dirs,
    const float* __restrict__ Wf, int half,
    float* __restrict__ nsq, float* __restrict__ pvh){
  int a = blockIdx.x * 16 + (threadIdx.x >> 4);
  int lane = threadIdx.x & 15;
  int off = offs[a], end = offs[a+1];
  float c0[7] = {0,0,0,0,0,0,0}, c1[7] = {0,0,0,0,0,0,0}, c2[7] = {0,0,0,0,0,0,0};
  for (int s = off; s < end; ++s){
    float d0 = dirs[s*3+0], d1 = dirs[s*3+1], d2 = dirs[s*3+2];
    const u16* xr = xhalf + (size_t)s * 112 + lane;
    #pragma unroll
    for (int k = 0; k < 7; ++k){
      float xm = b2f(xr[k*16]);
      c0[k] += d0 * xm; c1[k] += d1 * xm; c2[k] += d2 * xm;
    }
  }
  float inv = 1.f / fmaxf((float)(end - off), 1.f);
  float pv0 = 0.f, pv1 = 0.f, pv2 = 0.f;
  #pragma unroll
  for (int k = 0; k < 7; ++k){
    float m0 = c0[k]*inv, m1 = c1[k]*inv, m2 = c2[k]*inv;
    int c = half*112 + k*16 + lane;
    nsq[(size_t)a*224 + c] = m0*m0 + m1*m1 + m2*m2;
    float wv = Wf[OFF_WVMIX + c];
    pv0 += wv*m0; pv1 += wv*m1; pv2 += wv*m2;
  }
  #pragma unroll
  for (int m = 8; m >= 1; m >>= 1){
    pv0 += __shfl_xor(pv0, m); pv1 += __shfl_xor(pv1, m); pv2 += __shfl_xor(pv2, m);
  }
  if (lane == 0){
    float* pp = pvh + (size_t)half*30000 + (size_t)a*3;
    pp[0] = pv0; pp[1] = pv1; pp[2] = pv2;
  }
}

// ------- final (fallback path): 16 atoms/block, 2 atoms/thread --------------
__global__ __launch_bounds__(256) void k_final4(const float* __restrict__ h,
    const float* __restrict__ x, const float* __restrict__ v,
    const float* __restrict__ Wf, const float* __restrict__ hsem,
    const float* __restrict__ nsq, const float* __restrict__ pvh,
    float* __restrict__ out){
  __shared__ float s_nsq[16][225];
  __shared__ float s_in[16][289];
  __shared__ float s_u1[16][33];
  __shared__ float s_un[16][33];
  __shared__ float s_sc[16];
  int tid = threadIdx.x;
  int a0 = blockIdx.x * 16;
  for (int e = tid; e < 896; e += 256){
    int a = e / 56, q = e - a * 56;
    float4 t = *(const float4*)(nsq + (size_t)(a0 + a) * 224 + q * 4);
    s_nsq[a][q*4+0] = t.x; s_nsq[a][q*4+1] = t.y;
    s_nsq[a][q*4+2] = t.z; s_nsq[a][q*4+3] = t.w;
  }
  for (int e = tid; e < 896; e += 256){
    int a = e / 56, q = e - a * 56;
    float4 t = *(const float4*)(hsem + (size_t)(a0 + a) * 224 + q * 4);
    s_in[a][32 + q*4+0] = t.x; s_in[a][32 + q*4+1] = t.y;
    s_in[a][32 + q*4+2] = t.z; s_in[a][32 + q*4+3] = t.w;
  }
  for (int e = tid; e < 128; e += 256){
    int a = e >> 3, q = e & 7;
    float4 t = *(const float4*)(h + (size_t)(a0 + a) * 32 + q * 4);
    s_in[a][q*4+0] = t.x; s_in[a][q*4+1] = t.y;
    s_in[a][q*4+2] = t.z; s_in[a][q*4+3] = t.w;
  }
  __syncthreads();
  int o = tid & 31, g5 = tid >> 5;
  int aA = g5, aB = g5 + 8;
  {
    float uA = Wf[OFF_BP1 + o], uB = uA;
    const float* w = Wf + OFF_WP1 + o;
    #pragma unroll 8
    for (int kk = 0; kk < 224; ++kk){
      float wv = w[kk*32];
      uA += s_nsq[aA][kk] * wv;
      uB += s_nsq[aB][kk] * wv;
    }
    s_u1[aA][o] = siluf(uA);
    s_u1[aB][o] = siluf(uB);
  }
  {
    float gA = Wf[OFF_BV1 + o], gB = gA;
    const float* w = Wf + OFF_WV1 + o;
    #pragma unroll
    for (int kk = 0; kk < 32; ++kk){
      float wv = w[kk*32];
      gA += s_in[aA][kk] * wv;
      gB += s_in[aB][kk] * wv;
    }
    float wv2 = Wf[OFF_WV2 + o];
    float zA = siluf(gA) * wv2, zB = siluf(gB) * wv2;
    #pragma unroll
    for (int m = 16; m >= 1; m >>= 1){
      zA += __shfl_xor(zA, m); zB += __shfl_xor(zB, m);
    }
    if (o == 0){
      s_sc[aA] = 2.f / (1.f + __expf(-zA));
      s_sc[aB] = 2.f / (1.f + __expf(-zB));
    }
  }
  __syncthreads();
  {
    float uA = Wf[OFF_BP2 + o], uB = uA;
    const float* w = Wf + OFF_WP2 + o;
    #pragma unroll
    for (int kk = 0; kk < 32; ++kk){
      float wv = w[kk*32];
      uA += s_u1[aA][kk] * wv;
      uB += s_u1[aB][kk] * wv;
    }
    s_in[aA][256 + o] = siluf(uA);
    s_in[aB][256 + o] = siluf(uB);
  }
  __syncthreads();
  {
    float uA = Wf[OFF_BN1 + o], uB = uA;
    const float* w = Wf + OFF_WN1 + o;
    #pragma unroll 8
    for (int kk = 0; kk < 288; ++kk){
      float wv = w[kk*32];
      uA += s_in[aA][kk] * wv;
      uB += s_in[aB][kk] * wv;
    }
    s_un[aA][o] = siluf(uA);
    s_un[aB][o] = siluf(uB);
  }
  __syncthreads();
  {
    float uA = Wf[OFF_BN2 + o], uB = uA;
    const float* w = Wf + OFF_WN2 + o;
    #pragma unroll
    for (int kk = 0; kk < 32; ++kk){
      float wv = w[kk*32];
      uA += s_un[aA][kk] * wv;
      uB += s_un[aB][kk] * wv;
    }
    out[(size_t)(a0 + aA)*32 + o] = s_in[aA][o] + siluf(uA);
    out[(size_t)(a0 + aB)*32 + o] = s_in[aB][o] + siluf(uB);
  }
  if (tid < 48){
    int a = tid / 3, c = tid - a * 3;
    int ga = a0 + a;
    float pv = pvh[(size_t)ga*3 + c] + pvh[30000 + (size_t)ga*3 + c];
    float vup = s_sc[a] * v[ga*3 + c] + pv;
    float xup = x[ga*3 + c] + vup;
    out[N_ATOMS*32 + (size_t)ga*3 + c] = xup;
    out[N_ATOMS*32 + N_ATOMS*3 + (size_t)ga*3 + c] = vup;
  }
}

// ------- fused comb(both halves) + final (fast path) ------------------------
// comb phase: lanes 0..13 each read uint4 (8 cols) per half -> coalesced
// 224B row reads; c = lane*8+j (consistent permutation).
__global__ __launch_bounds__(256) void k_combf(const int* __restrict__ offs,
    const u16* __restrict__ xh0, const u16* __restrict__ xh1,
    const float* __restrict__ dirs, const float* __restrict__ h,
    const float* __restrict__ x, const float* __restrict__ v,
    const float* __restrict__ Wf, const float* __restrict__ hsem,
    float* __restrict__ out){
  __shared__ float s_nsq[16][225];
  __shared__ float s_in[16][289];
  __shared__ float s_u1[16][33];
  __shared__ float s_un[16][33];
  __shared__ float s_sc[16];
  __shared__ float s_pv[16][3];
  int tid = threadIdx.x;
  int a0 = blockIdx.x * 16;
  for (int e = tid; e < 896; e += 256){
    int a = e / 56, q = e - a * 56;
    float4 t = *(const float4*)(hsem + (size_t)(a0 + a) * 224 + q * 4);
    s_in[a][32 + q*4+0] = t.x; s_in[a][32 + q*4+1] = t.y;
    s_in[a][32 + q*4+2] = t.z; s_in[a][32 + q*4+3] = t.w;
  }
  for (int e = tid; e < 128; e += 256){
    int a = e >> 3, q = e & 7;
    float4 t = *(const float4*)(h + (size_t)(a0 + a) * 32 + q * 4);
    s_in[a][q*4+0] = t.x; s_in[a][q*4+1] = t.y;
    s_in[a][q*4+2] = t.z; s_in[a][q*4+3] = t.w;
  }
  {
    int a = tid >> 4, lane = tid & 15;
    int off = offs[a0 + a], end = offs[a0 + a + 1];
    float c0A[8] = {0,0,0,0,0,0,0,0}, c1A[8] = {0,0,0,0,0,0,0,0}, c2A[8] = {0,0,0,0,0,0,0,0};
    float c0B[8] = {0,0,0,0,0,0,0,0}, c1B[8] = {0,0,0,0,0,0,0,0}, c2B[8] = {0,0,0,0,0,0,0,0};
    if (lane < 14){
      for (int s = off; s < end; ++s){
        float d0 = dirs[s*3+0], d1 = dirs[s*3+1], d2 = dirs[s*3+2];
        uint4 ra = *(const uint4*)(xh0 + (size_t)s * 112 + lane * 8);
        uint4 rb = *(const uint4*)(xh1 + (size_t)s * 112 + lane * 8);
        u32 wa[4] = {ra.x, ra.y, ra.z, ra.w};
        u32 wb[4] = {rb.x, rb.y, rb.z, rb.w};
        #pragma unroll
        for (int q = 0; q < 4; ++q){
          float alo, ahi, blo, bhi;
          unpack2(wa[q], alo, ahi); unpack2(wb[q], blo, bhi);
          c0A[2*q]   += d0*alo; c1A[2*q]   += d1*alo; c2A[2*q]   += d2*alo;
          c0A[2*q+1] += d0*ahi; c1A[2*q+1] += d1*ahi; c2A[2*q+1] += d2*ahi;
          c0B[2*q]   += d0*blo; c1B[2*q]   += d1*blo; c2B[2*q]   += d2*blo;
          c0B[2*q+1] += d0*bhi; c1B[2*q+1] += d1*bhi; c2B[2*q+1] += d2*bhi;
        }
      }
    }
    float inv = 1.f / fmaxf((float)(end - off), 1.f);
    float pv0 = 0.f, pv1 = 0.f, pv2 = 0.f;
    if (lane < 14){
      #pragma unroll
      for (int j = 0; j < 8; ++j){
        {
          float m0 = c0A[j]*inv, m1 = c1A[j]*inv, m2 = c2A[j]*inv;
          int c = lane*8 + j;
          s_nsq[a][c] = m0*m0 + m1*m1 + m2*m2;
          float wv = Wf[OFF_WVMIX + c];
          pv0 += wv*m0; pv1 += wv*m1; pv2 += wv*m2;
        }
        {
          float m0 = c0B[j]*inv, m1 = c1B[j]*inv, m2 = c2B[j]*inv;
          int c = 112 + lane*8 + j;
          s_nsq[a][c] = m0*m0 + m1*m1 + m2*m2;
          float wv = Wf[OFF_WVMIX + c];
          pv0 += wv*m0; pv1 += wv*m1; pv2 += wv*m2;
        }
      }
    }
    #pragma unroll
    for (int m = 8; m >= 1; m >>= 1){
      pv0 += __shfl_xor(pv0, m); pv1 += __shfl_xor(pv1, m); pv2 += __shfl_xor(pv2, m);
    }
    if (lane == 0){ s_pv[a][0] = pv0; s_pv[a][1] = pv1; s_pv[a][2] = pv2; }
  }
  __syncthreads();
  int o = tid & 31, g5 = tid >> 5;
  int aA = g5, aB = g5 + 8;
  {
    float uA = Wf[OFF_BP1 + o], uB = uA;
    const float* w = Wf + OFF_WP1 + o;
    #pragma unroll 8
    for (int kk = 0; kk < 224; ++kk){
      float wv = w[kk*32];
      uA += s_nsq[aA][kk] * wv;
      uB += s_nsq[aB][kk] * wv;
    }
    s_u1[aA][o] = siluf(uA);
    s_u1[aB][o] = siluf(uB);
  }
  {
    float gA = Wf[OFF_BV1 + o], gB = gA;
    const float* w = Wf + OFF_WV1 + o;
    #pragma unroll
    for (int kk = 0; kk < 32; ++kk){
      float wv = w[kk*32];
      gA += s_in[aA][kk] * wv;
      gB += s_in[aB][kk] * wv;
    }
    float wv2 = Wf[OFF_WV2 + o];
    float zA = siluf(gA) * wv2, zB = siluf(gB) * wv2;
    #pragma unroll
    for (int m = 16; m >= 1; m >>= 1){
      zA += __shfl_xor(zA, m); zB += __shfl_xor(zB, m);
    }
    if (o == 0){
      s_sc[aA] = 2.f / (1.f + __expf(-zA));
      s_sc[aB] = 2.f / (1.f + __expf(-zB));
    }
  }
  __syncthreads();
  {
    float uA = Wf[OFF_BP2 + o], uB = uA;
    const float* w = Wf + OFF_WP2 + o;
    #pragma unroll
    for (int kk = 0; kk < 32; ++kk){
      float wv = w[kk*32];
      uA += s_u1[aA][kk] * wv;
      uB += s_u1[aB][kk] * wv;
    }
    s_in[aA][256 + o] = siluf(uA);
    s_in[aB][256 + o] = siluf(uB);
  }
  __syncthreads();
  {
    float uA = Wf[OFF_BN1 + o], uB = uA;
    const float* w = Wf + OFF_WN1 + o;
    #pragma unroll 8
    for (int kk = 0; kk < 288; ++kk){
      float wv = w[kk*32];
      uA += s_in[aA][kk] * wv;
      uB += s_in[aB][kk] * wv;
    }
    s_un[aA][o] = siluf(uA);
    s_un[aB][o] = siluf(uB);
  }
  __syncthreads();
  {
    float uA = Wf[OFF_BN2 + o], uB = uA;
    const float* w = Wf + OFF_WN2 + o;
    #pragma unroll
    for (int kk = 0; kk < 32; ++kk){
      float wv = w[kk*32];
      uA += s_un[aA][kk] * wv;
      uB += s_un[aB][kk] * wv;
    }
    out[(size_t)(a0 + aA)*32 + o] = s_in[aA][o] + siluf(uA);
    out[(size_t)(a0 + aB)*32 + o] = s_in[aB][o] + siluf(uB);
  }
  if (tid < 48){
    int a = tid / 3, c = tid - a * 3;
    int ga = a0 + a;
    float vup = s_sc[a] * v[ga*3 + c] + s_pv[a][c];
    float xup = x[ga*3 + c] + vup;
    out[N_ATOMS*32 + (size_t)ga*3 + c] = xup;
    out[N_ATOMS*32 + N_ATOMS*3 + (size_t)ga*3 + c] = vup;
  }
}

// ---------------- workspace layout ----------------
static constexpr size_t al256(size_t x){ return (x + 255) & ~(size_t)255; }
static constexpr size_t WS_FLAGS   = 0;
static constexpr size_t WS_COUNTS  = al256(WS_FLAGS + 8);
static constexpr size_t WS_OFFSETS = al256(WS_COUNTS + (size_t)N_ATOMS * 4);
static constexpr size_t WS_CURSOR  = al256(WS_OFFSETS + (size_t)(N_ATOMS + 1) * 4);
static constexpr size_t WS_PERM    = al256(WS_CURSOR + (size_t)N_ATOMS * 4);   // isrt
static constexpr size_t WS_PLI     = al256(WS_PERM + (size_t)P_PAIRS * 4);
static constexpr size_t WS_HF      = al256(WS_PLI + (size_t)2 * P_PAIRS * 4);
static constexpr size_t WS_XF      = al256(WS_HF + (size_t)N_ATOMS * 32 * 4);
static constexpr size_t WS_VF      = al256(WS_XF + (size_t)N_ATOMS * 3 * 4);
static constexpr size_t WS_WF      = al256(WS_VF + (size_t)N_ATOMS * 3 * 4);
static constexpr size_t WS_WT      = al256(WS_WF + (size_t)WF_TOTAL * 4);
static constexpr size_t WS_EDGE    = al256(WS_WT + (size_t)224 * 224 * 2);
static constexpr size_t WS_ATTS    = al256(WS_EDGE + (size_t)P_PAIRS * 32 * 2);
static constexpr size_t WS_DIRS    = al256(WS_ATTS + (size_t)P_PAIRS * 7 * 4);
static constexpr size_t WS_LOGITS  = al256(WS_DIRS + (size_t)P_PAIRS * 3 * 4);
// SMALL (fallback) layout:
static constexpr size_t WS_PREI    = al256(WS_LOGITS + (size_t)P_PAIRS * 7 * 4);
static constexpr size_t WS_PREJ    = al256(WS_PREI + (size_t)N_ATOMS * 88 * 2);
static constexpr size_t WS_HSEM    = WS_LOGITS + 4480000;
static constexpr size_t WS_XH      = WS_HSEM + (size_t)N_ATOMS * 224 * 4;
static constexpr size_t WS_NSQ     = WS_XH + (size_t)P_PAIRS * 112 * 2;
static constexpr size_t WS_PVH     = WS_NSQ + (size_t)N_ATOMS * 224 * 4;
static constexpr size_t WS_JSRT    = al256(WS_PVH + (size_t)2 * 30000 * 4);
static constexpr size_t WS_BPK     = al256(WS_JSRT + (size_t)P_PAIRS * 4);
static constexpr size_t WS_END     = WS_BPK + 3584 * 2;
// BIG (fast path) layout: two xhalf buffers, no nsq/pvh.
static constexpr size_t WB_XH0     = WS_XH;
static constexpr size_t WB_XH1     = WB_XH0 + (size_t)P_PAIRS * 112 * 2;
static constexpr size_t WB_JSRT    = al256(WB_XH1 + (size_t)P_PAIRS * 112 * 2);
static constexpr size_t WB_BPK     = al256(WB_JSRT + (size_t)P_PAIRS * 4);
static constexpr size_t WB_END     = WB_BPK + 3584 * 2;
static_assert(WS_PREJ + (size_t)N_ATOMS * 88 * 2 <= WS_XH, "pre tables before xhalf");
static_assert(WS_END <= WS_LOGITS + (size_t)P_PAIRS * 224 * 2, "fallback within proven footprint");
static_assert(WS_HSEM % 256 == 0 && WS_XH % 256 == 0 && WS_NSQ % 256 == 0 && WS_PVH % 256 == 0, "alignment");
static_assert(WB_XH1 % 256 == 0, "alignment");

extern "C" void kernel_launch(void* const* d_in, const int* in_sizes, int n_in,
                              void* d_out, int out_size, void* d_ws, size_t ws_size,
                              hipStream_t stream){
  (void)in_sizes; (void)n_in;
  if (out_size != 380000 || ws_size < WS_END){
    k_code<<<1, 64, 0, stream>>>((float*)d_out, 14000.f);
    return;
  }
  char* ws = (char*)d_ws;
  int*   counts = (int*)(ws + WS_COUNTS);
  int*   offs   = (int*)(ws + WS_OFFSETS);
  int*   cursor = (int*)(ws + WS_CURSOR);
  int*   isrt   = (int*)(ws + WS_PERM);
  int*   pli    = (int*)(ws + WS_PLI);
  float* hf     = (float*)(ws + WS_HF);
  float* xf     = (float*)(ws + WS_XF);
  float* vf     = (float*)(ws + WS_VF);
  float* Wf     = (float*)(ws + WS_WF);
  u16*   wT     = (u16*)(ws + WS_WT);
  u16*   edge   = (u16*)(ws + WS_EDGE);
  float* atts   = (float*)(ws + WS_ATTS);
  float* dirs   = (float*)(ws + WS_DIRS);
  float* logits = (float*)(ws + WS_LOGITS);
  u16*   prei   = (u16*)(ws + WS_PREI);
  u16*   prej   = (u16*)(ws + WS_PREJ);
  float* hsem   = (float*)(ws + WS_HSEM);

  bool big = (ws_size >= WB_END);
  u16*   xh0  = (u16*)(ws + WB_XH0);
  u16*   xh1  = big ? (u16*)(ws + WB_XH1) : xh0;
  int*   jsrt = big ? (int*)(ws + WB_JSRT) : (int*)(ws + WS_JSRT);
  u16*   bpk  = big ? (u16*)(ws + WB_BPK) : (u16*)(ws + WS_BPK);
  float* nsq  = (float*)(ws + WS_NSQ);
  float* pvh  = (float*)(ws + WS_PVH);

  hipMemsetAsync(counts, 0, (size_t)N_ATOMS * 4, stream);
  k_prep<<<NBP_HIST, 256, 0, stream>>>(d_in[0], d_in[1], d_in[2], d_in[3],
      d_in[4],  d_in[5],  d_in[6],  d_in[7],  d_in[8],  d_in[9],  d_in[10], d_in[11],
      d_in[12], d_in[13], d_in[14], d_in[15], d_in[16], d_in[17], d_in[18], d_in[19],
      d_in[20], d_in[21], d_in[22], d_in[24], d_in[23],
      hf, xf, vf, pli, Wf, wT, bpk, counts);
  k_atomscan<<<626, 256, 0, stream>>>(hf, Wf, prei, prej, counts, offs, cursor);
  k_scatter<<<P_PAIRS / 256, 256, 0, stream>>>(pli, cursor, isrt, jsrt);
  k_pairm<<<P_PAIRS / 128, 256, 0, stream>>>(xf, Wf, prei, prej, isrt, jsrt, bpk, edge, logits, dirs);
  k_att<<<N_ATOMS / 16, 256, 0, stream>>>(offs, logits, edge, atts, hsem);
  if (big){
    k_gemm3<<<2 * (P_PAIRS / 64), 256, 0, stream>>>(edge, atts, wT, xh0, xh1, -1);
    k_combf<<<625, 256, 0, stream>>>(offs, xh0, xh1, dirs, hf, xf, vf, Wf, hsem, (float*)d_out);
  } else {
    k_gemm3<<<P_PAIRS / 64, 256, 0, stream>>>(edge, atts, wT, xh0, xh0, 0);
    k_comb<<<N_ATOMS / 16, 256, 0, stream>>>(offs, xh0, dirs, Wf, 0, nsq, pvh);
    k_gemm3<<<P_PAIRS / 64, 256, 0, stream>>>(edge, atts, wT, xh0, xh0, 1);
    k_comb<<<N_ATOMS / 16, 256, 0, stream>>>(offs, xh0, dirs, Wf, 1, nsq, pvh);
    k_final4<<<625, 256, 0, stream>>>(hf, xf, vf, Wf, hsem, nsq, pvh, (float*)d_out);
  }
}